// Round 1
// baseline (489.298 us; speedup 1.0000x reference)
//
#include <hip/hip_runtime.h>
#include <hip/hip_bf16.h>
#include <math.h>

typedef __bf16 bf16;
typedef __bf16 bf16x4 __attribute__((ext_vector_type(4)));
typedef __bf16 bf16x8 __attribute__((ext_vector_type(8)));
typedef float f32x4 __attribute__((ext_vector_type(4)));

static constexpr int N_TOK = 2048;
static constexpr int B_SZ = 8;
static constexpr int D_MODEL = 256;

#define MFMA(a, b, c) __builtin_amdgcn_mfma_f32_16x16x32_bf16((a), (b), (c), 0, 0, 0)

// A/B operand fragment: two stacked K=16 slices.
// element j (0..7): k = 16*(j>>2) + ((lane>>4)<<2) + (j&3), row/col = lane&15
__device__ __forceinline__ bf16x8 load_frag(const bf16* rowp, int lane) {
  const int g = (lane >> 4) << 2;
  bf16x4 lo = *(const bf16x4*)(rowp + g);
  bf16x4 hi = *(const bf16x4*)(rowp + g + 16);
  return __builtin_shufflevector(lo, hi, 0, 1, 2, 3, 4, 5, 6, 7);
}

// ---------------- fp32 -> bf16 convert ----------------
__global__ void f2b_kernel(const float* __restrict__ in, bf16* __restrict__ out, int n) {
  int i = blockIdx.x * 256 + threadIdx.x;
  if (i < n) out[i] = (bf16)in[i];
}

// ---------------- conv1x1 GEMM: Out[b] = W(MxK) * In[b](KxN) + bias ----------------
// In is optionally a channel-concat of In0 (first C0 ch) and In1 (rest).
__global__ __launch_bounds__(256) void gemm_conv(
    const bf16* __restrict__ W, const bf16* __restrict__ In0,
    const bf16* __restrict__ In1, int C0, const float* __restrict__ bias,
    bf16* __restrict__ outb, float* __restrict__ outf, int M, int K) {
  const int n0 = blockIdx.x * 64;
  const int m0 = blockIdx.y * 64;
  const int b = blockIdx.z;
  const int t = threadIdx.x;
  const int lane = t & 63;
  const int w = t >> 6;
  const int wm = (w >> 1) * 32, wn = (w & 1) * 32;

  __shared__ bf16 As[64][48];  // [m][k], padded: 96B row stride (16B multiple)
  __shared__ bf16 Bs[64][48];  // [n][k] (transposed so k is contiguous per lane)

  f32x4 acc[2][2] = {};

  const int ai = t >> 2, ac = (t & 3) * 8;
  const int bk = t >> 3, bn = (t & 7) * 8;

  for (int k0 = 0; k0 < K; k0 += 32) {
    __syncthreads();
    *(bf16x8*)&As[ai][ac] = *(const bf16x8*)(W + (size_t)(m0 + ai) * K + k0 + ac);
    {
      int ch = k0 + bk;
      const bf16* src = (ch < C0)
          ? In0 + ((size_t)b * C0 + ch) * N_TOK + n0 + bn
          : In1 + ((size_t)b * (K - C0) + (ch - C0)) * N_TOK + n0 + bn;
      bf16x8 v = *(const bf16x8*)src;
#pragma unroll
      for (int j = 0; j < 8; ++j) Bs[bn + j][bk] = v[j];
    }
    __syncthreads();
    bf16x8 a0 = load_frag(&As[wm + (lane & 15)][0], lane);
    bf16x8 a1 = load_frag(&As[wm + 16 + (lane & 15)][0], lane);
    bf16x8 b0 = load_frag(&Bs[wn + (lane & 15)][0], lane);
    bf16x8 b1 = load_frag(&Bs[wn + 16 + (lane & 15)][0], lane);
    acc[0][0] = MFMA(a0, b0, acc[0][0]);
    acc[0][1] = MFMA(a0, b1, acc[0][1]);
    acc[1][0] = MFMA(a1, b0, acc[1][0]);
    acc[1][1] = MFMA(a1, b1, acc[1][1]);
  }

#pragma unroll
  for (int fm = 0; fm < 2; ++fm)
#pragma unroll
    for (int fn = 0; fn < 2; ++fn)
#pragma unroll
      for (int r = 0; r < 4; ++r) {
        int m = m0 + wm + fm * 16 + ((lane >> 4) << 2) + r;
        int n = n0 + wn + fn * 16 + (lane & 15);
        float v = acc[fm][fn][r] + bias[m];
        size_t idx = ((size_t)b * M + m) * N_TOK + n;
        if (outf) outf[idx] = v;
        else outb[idx] = (bf16)v;
      }
}

// ---------------- flash attention over heads (hd=64, H=4) ----------------
// channel for (d,h) is d*4+h (reshape(B, hd, H, N) semantics)
__global__ __launch_bounds__(256) void attn_kernel(
    const bf16* __restrict__ q, const bf16* __restrict__ k,
    const bf16* __restrict__ v, bf16* __restrict__ attn) {
  const int n0 = blockIdx.x * 64;
  const int h = blockIdx.y;
  const int b = blockIdx.z;
  const int t = threadIdx.x;
  const int lane = t & 63;
  const int w = t >> 6;

  __shared__ bf16 Aq[64][72];  // [n][d]  (Q^T)
  __shared__ bf16 Kt[64][72];  // [m][d]  (K^T)
  __shared__ bf16 Vd[64][72];  // [d][m]  (V, k=m contiguous for B operand)
  __shared__ bf16 Pl[64][72];  // [n][m]  (P for PV A operand)

  // stage Q^T
#pragma unroll
  for (int i = 0; i < 16; ++i) {
    int d = i * 4 + w;
    Aq[lane][d] = q[((size_t)b * D_MODEL + d * 4 + h) * N_TOK + n0 + lane];
  }

  float mold[4], lsum[4];
  f32x4 o[4] = {};
#pragma unroll
  for (int r = 0; r < 4; ++r) { mold[r] = -INFINITY; lsum[r] = 0.f; }

  const int vd_d = t >> 2, vd_s = (t & 3) * 16;

  for (int mt = 0; mt < 32; ++mt) {
    const int m0 = mt * 64;
    __syncthreads();
#pragma unroll
    for (int i = 0; i < 16; ++i) {
      int d = i * 4 + w;
      Kt[lane][d] = k[((size_t)b * D_MODEL + d * 4 + h) * N_TOK + m0 + lane];
    }
    {
      const bf16* src = v + ((size_t)b * D_MODEL + vd_d * 4 + h) * N_TOK + m0 + vd_s;
      *(bf16x8*)&Vd[vd_d][vd_s] = *(const bf16x8*)src;
      *(bf16x8*)&Vd[vd_d][vd_s + 8] = *(const bf16x8*)(src + 8);
    }
    __syncthreads();

    // S = (Q^T K) / 8 ; each wave owns 16 n-rows x 64 m-cols
    f32x4 s[4];
#pragma unroll
    for (int f = 0; f < 4; ++f) {
      s[f] = (f32x4){0.f, 0.f, 0.f, 0.f};
#pragma unroll
      for (int ks = 0; ks < 2; ++ks) {
        bf16x8 a = load_frag(&Aq[16 * w + (lane & 15)][ks * 32], lane);
        bf16x8 bb = load_frag(&Kt[16 * f + (lane & 15)][ks * 32], lane);
        s[f] = MFMA(a, bb, s[f]);
      }
#pragma unroll
      for (int r = 0; r < 4; ++r) s[f][r] *= 0.125f;
    }

    // online softmax: row r of a fragment lives in one 16-lane group
    float mx[4];
#pragma unroll
    for (int r = 0; r < 4; ++r)
      mx[r] = fmaxf(fmaxf(s[0][r], s[1][r]), fmaxf(s[2][r], s[3][r]));
#pragma unroll
    for (int xm = 1; xm <= 8; xm <<= 1)
#pragma unroll
      for (int r = 0; r < 4; ++r) mx[r] = fmaxf(mx[r], __shfl_xor(mx[r], xm));

    float fac[4], rs[4] = {0.f, 0.f, 0.f, 0.f};
#pragma unroll
    for (int r = 0; r < 4; ++r) {
      float mn = fmaxf(mold[r], mx[r]);
      fac[r] = __expf(mold[r] - mn);  // first tile: exp(-inf)=0
      mold[r] = mn;
    }
#pragma unroll
    for (int f = 0; f < 4; ++f)
#pragma unroll
      for (int r = 0; r < 4; ++r) {
        float p = __expf(s[f][r] - mold[r]);
        rs[r] += p;
        Pl[16 * w + ((lane >> 4) << 2) + r][16 * f + (lane & 15)] = (bf16)p;
      }
#pragma unroll
    for (int xm = 1; xm <= 8; xm <<= 1)
#pragma unroll
      for (int r = 0; r < 4; ++r) rs[r] += __shfl_xor(rs[r], xm);
#pragma unroll
    for (int r = 0; r < 4; ++r) lsum[r] = lsum[r] * fac[r] + rs[r];
#pragma unroll
    for (int f2 = 0; f2 < 4; ++f2)
#pragma unroll
      for (int r = 0; r < 4; ++r) o[f2][r] *= fac[r];
    __syncthreads();

    // O += P * V^T
#pragma unroll
    for (int f2 = 0; f2 < 4; ++f2)
#pragma unroll
      for (int ks = 0; ks < 2; ++ks) {
        bf16x8 a = load_frag(&Pl[16 * w + (lane & 15)][ks * 32], lane);
        bf16x8 bb = load_frag(&Vd[16 * f2 + (lane & 15)][ks * 32], lane);
        o[f2] = MFMA(a, bb, o[f2]);
      }
  }

#pragma unroll
  for (int f2 = 0; f2 < 4; ++f2)
#pragma unroll
    for (int r = 0; r < 4; ++r) {
      int row = 16 * w + ((lane >> 4) << 2) + r;
      int d = 16 * f2 + (lane & 15);
      float val = o[f2][r] / lsum[r];
      attn[((size_t)b * D_MODEL + d * 4 + h) * N_TOK + n0 + row] = (bf16)val;
    }
}

// ---------------- BatchNorm (training stats) ----------------
__global__ __launch_bounds__(256) void bn_stats_kernel(
    const bf16* __restrict__ h, float* __restrict__ mean_out,
    float* __restrict__ istd_out) {
  const int c = blockIdx.x;  // 0..511
  const int t = threadIdx.x;
  float s = 0.f, ss = 0.f;
  for (int i = t; i < B_SZ * N_TOK; i += 256) {
    int b = i >> 11, n = i & (N_TOK - 1);
    float v = (float)h[((size_t)b * 512 + c) * N_TOK + n];
    s += v;
    ss += v * v;
  }
#pragma unroll
  for (int xm = 1; xm < 64; xm <<= 1) {
    s += __shfl_xor(s, xm);
    ss += __shfl_xor(ss, xm);
  }
  __shared__ float red[8];
  const int w = t >> 6, lane = t & 63;
  if (lane == 0) { red[w] = s; red[4 + w] = ss; }
  __syncthreads();
  if (t == 0) {
    s = red[0] + red[1] + red[2] + red[3];
    ss = red[4] + red[5] + red[6] + red[7];
    const float inv = 1.f / (float)(B_SZ * N_TOK);
    float mu = s * inv;
    float var = ss * inv - mu * mu;
    mean_out[c] = mu;
    istd_out[c] = rsqrtf(var + 1e-3f);
  }
}

__global__ void bn_norm_kernel(bf16* __restrict__ h, const float* __restrict__ mean,
                               const float* __restrict__ istd,
                               const float* __restrict__ gamma,
                               const float* __restrict__ beta) {
  size_t i = (size_t)blockIdx.x * 256 + threadIdx.x;
  int c = (int)((i >> 11) & 511);
  float v = (float)h[i];
  v = (v - mean[c]) * istd[c] * gamma[c] + beta[c];
  h[i] = (bf16)fmaxf(v, 0.f);
}

extern "C" void kernel_launch(void* const* d_in, const int* in_sizes, int n_in,
                              void* d_out, int out_size, void* d_ws, size_t ws_size,
                              hipStream_t stream) {
  (void)in_sizes; (void)n_in; (void)out_size; (void)ws_size;
  const float* x = (const float*)d_in[0];
  const float* source = (const float*)d_in[1];
  const float* Wq = (const float*)d_in[2];
  const float* bq = (const float*)d_in[3];
  const float* Wk = (const float*)d_in[4];
  const float* bk = (const float*)d_in[5];
  const float* Wv = (const float*)d_in[6];
  const float* bv = (const float*)d_in[7];
  const float* Wm = (const float*)d_in[8];
  const float* bm = (const float*)d_in[9];
  const float* W1 = (const float*)d_in[10];
  const float* b1 = (const float*)d_in[11];
  const float* gamma1 = (const float*)d_in[12];
  const float* beta1 = (const float*)d_in[13];
  const float* W2 = (const float*)d_in[14];
  const float* b2 = (const float*)d_in[15];
  float* out = (float*)d_out;

  char* p = (char*)d_ws;
  size_t off = 0;
  auto alloc = [&](size_t bytes) {
    void* r = p + off;
    off += (bytes + 255) & ~(size_t)255;
    return r;
  };
  const size_t feat = (size_t)B_SZ * D_MODEL * N_TOK;  // 4,194,304 elems
  bf16* xb = (bf16*)alloc(feat * 2);
  bf16* sb = (bf16*)alloc(feat * 2);
  bf16* qb = (bf16*)alloc(feat * 2);
  bf16* kb = (bf16*)alloc(feat * 2);
  bf16* vb = (bf16*)alloc(feat * 2);
  bf16* ab = (bf16*)alloc(feat * 2);
  bf16* mb = (bf16*)alloc(feat * 2);
  bf16* hb = (bf16*)alloc(feat * 4);  // [8][512][2048] bf16
  bf16* Wqb = (bf16*)alloc(65536 * 2);
  bf16* Wkb = (bf16*)alloc(65536 * 2);
  bf16* Wvb = (bf16*)alloc(65536 * 2);
  bf16* Wmb = (bf16*)alloc(65536 * 2);
  bf16* W1b = (bf16*)alloc(262144 * 2);
  bf16* W2b = (bf16*)alloc(131072 * 2);
  float* mean = (float*)alloc(512 * 4);
  float* istd = (float*)alloc(512 * 4);

  auto cvt = [&](const float* src, bf16* dst, int n) {
    f2b_kernel<<<(n + 255) / 256, 256, 0, stream>>>(src, dst, n);
  };
  cvt(x, xb, (int)feat);
  cvt(source, sb, (int)feat);
  cvt(Wq, Wqb, 65536);
  cvt(Wk, Wkb, 65536);
  cvt(Wv, Wvb, 65536);
  cvt(Wm, Wmb, 65536);
  cvt(W1, W1b, 262144);
  cvt(W2, W2b, 131072);

  dim3 blk(256);
  dim3 g256(32, 4, 8);
  // q/k/v projections
  gemm_conv<<<g256, blk, 0, stream>>>(Wqb, xb, nullptr, 256, bq, qb, nullptr, 256, 256);
  gemm_conv<<<g256, blk, 0, stream>>>(Wkb, sb, nullptr, 256, bk, kb, nullptr, 256, 256);
  gemm_conv<<<g256, blk, 0, stream>>>(Wvb, sb, nullptr, 256, bv, vb, nullptr, 256, 256);

  attn_kernel<<<dim3(32, 4, 8), blk, 0, stream>>>(qb, kb, vb, ab);

  // message projection
  gemm_conv<<<g256, blk, 0, stream>>>(Wmb, ab, nullptr, 256, bm, mb, nullptr, 256, 256);
  // MLP layer 1 on concat([x, message])
  gemm_conv<<<dim3(32, 8, 8), blk, 0, stream>>>(W1b, xb, mb, 256, b1, hb, nullptr, 512, 512);

  bn_stats_kernel<<<512, blk, 0, stream>>>(hb, mean, istd);
  bn_norm_kernel<<<(int)(feat * 2 / 256), blk, 0, stream>>>(hb, mean, istd, gamma1, beta1);

  // MLP layer 2 -> fp32 output
  gemm_conv<<<g256, blk, 0, stream>>>(W2b, hb, nullptr, 512, b2, nullptr, out, 256, 512);
}

// Round 2
// 469.016 us; speedup vs baseline: 1.0432x; 1.0432x over previous
//
#include <hip/hip_runtime.h>
#include <hip/hip_bf16.h>
#include <math.h>

typedef __bf16 bf16;
typedef __bf16 bf16x4 __attribute__((ext_vector_type(4)));
typedef __bf16 bf16x8 __attribute__((ext_vector_type(8)));
typedef float f32x4 __attribute__((ext_vector_type(4)));

static constexpr int N_TOK = 2048;
static constexpr int B_SZ = 8;

#define MFMA(a, b, c) __builtin_amdgcn_mfma_f32_16x16x32_bf16((a), (b), (c), 0, 0, 0)

// A/B operand fragment from a k-contiguous row: elem j -> k = 16*(j>>2) + ((lane>>4)<<2) + (j&3)
__device__ __forceinline__ bf16x8 load_frag(const bf16* rowp, int lane) {
  const int g = (lane >> 4) << 2;
  bf16x4 lo = *(const bf16x4*)(rowp + g);
  bf16x4 hi = *(const bf16x4*)(rowp + g + 16);
  return __builtin_shufflevector(lo, hi, 0, 1, 2, 3, 4, 5, 6, 7);
}

// ---------------- transpose + convert: [b][256][2048] f32 -> [b][2048][256] bf16 ----------------
__global__ __launch_bounds__(256) void transpose_cvt(const float* __restrict__ in,
                                                     bf16* __restrict__ outT) {
  const int n0 = blockIdx.x * 64, c0 = blockIdx.y * 64, b = blockIdx.z;
  const int t = threadIdx.x;
  __shared__ bf16 T[64][72];
  {
    int c = t >> 2, nc = (t & 3) * 16;
    const float* src = in + ((long)b * 256 + c0 + c) * N_TOK + n0 + nc;
#pragma unroll
    for (int q = 0; q < 4; ++q) {
      float4 v = *(const float4*)(src + q * 4);
      T[c][nc + q * 4 + 0] = (bf16)v.x;
      T[c][nc + q * 4 + 1] = (bf16)v.y;
      T[c][nc + q * 4 + 2] = (bf16)v.z;
      T[c][nc + q * 4 + 3] = (bf16)v.w;
    }
  }
  __syncthreads();
  {
    int n = t >> 2, cc = (t & 3) * 16;
    bf16x8 o0, o1;
#pragma unroll
    for (int j = 0; j < 8; ++j) { o0[j] = T[cc + j][n]; o1[j] = T[cc + 8 + j][n]; }
    bf16* dst = outT + ((long)b * N_TOK + n0 + n) * 256 + c0 + cc;
    *(bf16x8*)dst = o0;
    *(bf16x8*)(dst + 8) = o1;
  }
}

// ---------------- weight prep: convert + head permutation ----------------
// perm(c') = (c'&63)*4 + (c'>>6)   (c' = h*64+d  <->  c = d*4+h)
__global__ void prep_kernel(const float* __restrict__ Wq, const float* __restrict__ Wk,
                            const float* __restrict__ Wv, const float* __restrict__ Wm,
                            const float* __restrict__ W1, const float* __restrict__ W2,
                            const float* __restrict__ bq, const float* __restrict__ bk,
                            const float* __restrict__ bv,
                            bf16* __restrict__ Wqp, bf16* __restrict__ Wkp,
                            bf16* __restrict__ Wvp, bf16* __restrict__ Wmp,
                            bf16* __restrict__ W1b, bf16* __restrict__ W2b,
                            float* __restrict__ bqp, float* __restrict__ bkp,
                            float* __restrict__ bvp) {
  int i = blockIdx.x * 256 + threadIdx.x;
  if (i < 65536) {
    int cp = i >> 8, k = i & 255;
    int src = (((cp & 63) << 2) | (cp >> 6)) * 256 + k;
    Wqp[i] = (bf16)Wq[src];
    Wkp[i] = (bf16)Wk[src];
    Wvp[i] = (bf16)Wv[src];
    int m = i >> 8, c2 = i & 255;
    Wmp[i] = (bf16)Wm[m * 256 + (((c2 & 63) << 2) | (c2 >> 6))];
  } else if (i < 65536 + 262144) {
    int j = i - 65536;
    W1b[j] = (bf16)W1[j];
  } else if (i < 65536 + 262144 + 131072) {
    int j = i - 327680;
    W2b[j] = (bf16)W2[j];
  } else if (i < 65536 + 262144 + 131072 + 256) {
    int c2 = i - 458752;
    int src = (c2 & 63) * 4 + (c2 >> 6);
    bqp[c2] = bq[src];
    bkp[c2] = bk[src];
    bvp[c2] = bv[src];
  }
}

// ---------------- generic TN GEMM: C[i][j] = sum_k A[i][k] * B[j][k] + bias ----------------
// A rows optionally concat along k: k < cSplit from A0 (row stride cSplit), else A1 (row stride K-cSplit).
// B rows have stride K. Output C at out + b*batchOut + i*outR + j (bf16 or f32).
__global__ __launch_bounds__(256) void gemm_tn(
    const bf16* __restrict__ A0, const bf16* __restrict__ A1, int cSplit, long batchA,
    const bf16* __restrict__ B, long batchB,
    const float* __restrict__ bias, int biasOnCol,
    void* __restrict__ outp, int outF32, long outR, long batchOut, int K) {
  const int j0 = blockIdx.x * 64;
  const int i0 = blockIdx.y * 64;
  const int b = blockIdx.z;
  const int t = threadIdx.x;
  const int lane = t & 63, w = t >> 6;
  const int wi = (w >> 1) * 32, wj = (w & 1) * 32;
  __shared__ bf16 As[64][40], Bs[64][40];
  f32x4 acc[2][2] = {};
  const int sr = t >> 2, sc = (t & 3) * 8;
  const bf16* A0b = A0 + (long)b * batchA;
  const bf16* A1b = A1 ? A1 + (long)b * batchA : nullptr;
  const bf16* Bb = B + (long)b * batchB;

  for (int k0 = 0; k0 < K; k0 += 32) {
    __syncthreads();
    int kk = k0 + sc;
    const bf16* asrc = (kk < cSplit) ? A0b + (long)(i0 + sr) * cSplit + kk
                                     : A1b + (long)(i0 + sr) * (K - cSplit) + (kk - cSplit);
    *(bf16x8*)&As[sr][sc] = *(const bf16x8*)asrc;
    *(bf16x8*)&Bs[sr][sc] = *(const bf16x8*)(Bb + (long)(j0 + sr) * K + kk);
    __syncthreads();
    bf16x8 a0 = load_frag(&As[wi + (lane & 15)][0], lane);
    bf16x8 a1 = load_frag(&As[wi + 16 + (lane & 15)][0], lane);
    bf16x8 b0 = load_frag(&Bs[wj + (lane & 15)][0], lane);
    bf16x8 b1 = load_frag(&Bs[wj + 16 + (lane & 15)][0], lane);
    acc[0][0] = MFMA(a0, b0, acc[0][0]);
    acc[0][1] = MFMA(a0, b1, acc[0][1]);
    acc[1][0] = MFMA(a1, b0, acc[1][0]);
    acc[1][1] = MFMA(a1, b1, acc[1][1]);
  }

  float* outf = (float*)outp;
  bf16* outb = (bf16*)outp;
  const int g4 = (lane >> 4) << 2;
#pragma unroll
  for (int fm = 0; fm < 2; ++fm)
#pragma unroll
    for (int fn = 0; fn < 2; ++fn)
#pragma unroll
      for (int r = 0; r < 4; ++r) {
        int i = i0 + wi + fm * 16 + g4 + r;
        int j = j0 + wj + fn * 16 + (lane & 15);
        float v = acc[fm][fn][r] + (bias ? bias[biasOnCol ? j : i] : 0.f);
        long idx = (long)b * batchOut + (long)i * outR + j;
        if (outF32) outf[idx] = v;
        else outb[idx] = (bf16)v;
      }
}

// ---------------- flash attention v2 (all operands k-contiguous) ----------------
// qT/kT: [b][n][c'=h*64+d] token-major ; Vp: [b][c'][m] channel-major ; out aT: [b][n][c']
__global__ __launch_bounds__(256) void attn2_kernel(
    const bf16* __restrict__ qT, const bf16* __restrict__ kT,
    const bf16* __restrict__ Vp, bf16* __restrict__ aT) {
  const int n0 = blockIdx.x * 64;
  const int h = blockIdx.y, b = blockIdx.z;
  const int t = threadIdx.x, lane = t & 63, w = t >> 6;
  const int g4 = (lane >> 4) << 2;
  __shared__ bf16 Qs[64][72], Ks[64][72], Vs[64][72], Ps[64][72];
  const int sr = t >> 2, sc = (t & 3) * 16;
  const float SCL = 0.125f * 1.44269504088896340736f;  // 1/sqrt(64) * log2(e)

  {  // stage Q (scaled)
    const bf16* src = qT + ((long)(b * N_TOK + n0 + sr)) * 256 + h * 64 + sc;
    bf16x8 v0 = *(const bf16x8*)src, v1 = *(const bf16x8*)(src + 8);
#pragma unroll
    for (int j = 0; j < 8; ++j) {
      Qs[sr][sc + j] = (bf16)((float)v0[j] * SCL);
      Qs[sr][sc + 8 + j] = (bf16)((float)v1[j] * SCL);
    }
  }

  float m_r[4], l_r[4];
  f32x4 o[4] = {};
#pragma unroll
  for (int r = 0; r < 4; ++r) { m_r[r] = -INFINITY; l_r[r] = 0.f; }

  for (int mt = 0; mt < 32; ++mt) {
    const int m0 = mt * 64;
    __syncthreads();
    {  // stage K tile [64m][64d]
      const bf16* src = kT + ((long)(b * N_TOK + m0 + sr)) * 256 + h * 64 + sc;
      *(bf16x8*)&Ks[sr][sc] = *(const bf16x8*)src;
      *(bf16x8*)&Ks[sr][sc + 8] = *(const bf16x8*)(src + 8);
    }
    {  // stage V tile [64d][64m]
      const bf16* src = Vp + ((long)(b * 256 + h * 64 + sr)) * N_TOK + m0 + sc;
      *(bf16x8*)&Vs[sr][sc] = *(const bf16x8*)src;
      *(bf16x8*)&Vs[sr][sc + 8] = *(const bf16x8*)(src + 8);
    }
    __syncthreads();

    // S (log2-scaled): wave w owns rows 16w..16w+15 of n
    f32x4 s[4];
#pragma unroll
    for (int f = 0; f < 4; ++f) {
      s[f] = (f32x4){0.f, 0.f, 0.f, 0.f};
#pragma unroll
      for (int ks = 0; ks < 2; ++ks) {
        bf16x8 a = load_frag(&Qs[16 * w + (lane & 15)][ks * 32], lane);
        bf16x8 bb = load_frag(&Ks[16 * f + (lane & 15)][ks * 32], lane);
        s[f] = MFMA(a, bb, s[f]);
      }
    }

    float mx[4];
#pragma unroll
    for (int r = 0; r < 4; ++r)
      mx[r] = fmaxf(fmaxf(s[0][r], s[1][r]), fmaxf(s[2][r], s[3][r]));
#pragma unroll
    for (int xm = 1; xm <= 8; xm <<= 1)
#pragma unroll
      for (int r = 0; r < 4; ++r) mx[r] = fmaxf(mx[r], __shfl_xor(mx[r], xm));

    float fac[4], rs[4] = {0.f, 0.f, 0.f, 0.f};
#pragma unroll
    for (int r = 0; r < 4; ++r) {
      float mn = fmaxf(m_r[r], mx[r]);
      fac[r] = exp2f(m_r[r] - mn);
      m_r[r] = mn;
    }
#pragma unroll
    for (int f = 0; f < 4; ++f)
#pragma unroll
      for (int r = 0; r < 4; ++r) {
        float p = exp2f(s[f][r] - m_r[r]);
        rs[r] += p;
        Ps[16 * w + g4 + r][16 * f + (lane & 15)] = (bf16)p;
      }
#pragma unroll
    for (int xm = 1; xm <= 8; xm <<= 1)
#pragma unroll
      for (int r = 0; r < 4; ++r) rs[r] += __shfl_xor(rs[r], xm);
#pragma unroll
    for (int r = 0; r < 4; ++r) l_r[r] = l_r[r] * fac[r] + rs[r];
#pragma unroll
    for (int f2 = 0; f2 < 4; ++f2)
#pragma unroll
      for (int r = 0; r < 4; ++r) o[f2][r] *= fac[r];
    __syncthreads();

    // O += P @ V^T : A = P rows [n][m], B = V rows [d][m]
#pragma unroll
    for (int f2 = 0; f2 < 4; ++f2)
#pragma unroll
      for (int ks = 0; ks < 2; ++ks) {
        bf16x8 a = load_frag(&Ps[16 * w + (lane & 15)][ks * 32], lane);
        bf16x8 bb = load_frag(&Vs[16 * f2 + (lane & 15)][ks * 32], lane);
        o[f2] = MFMA(a, bb, o[f2]);
      }
  }

  float inv[4];
#pragma unroll
  for (int r = 0; r < 4; ++r) inv[r] = 1.f / l_r[r];
#pragma unroll
  for (int f2 = 0; f2 < 4; ++f2)
#pragma unroll
    for (int r = 0; r < 4; ++r) {
      int n = n0 + 16 * w + g4 + r;
      int d = 16 * f2 + (lane & 15);
      aT[((long)(b * N_TOK + n)) * 256 + h * 64 + d] = (bf16)(o[f2][r] * inv[r]);
    }
}

// ---------------- BatchNorm on token-major hT [16384][512] ----------------
__global__ __launch_bounds__(256) void bn_stats2(const bf16* __restrict__ hT,
                                                 float* __restrict__ mean,
                                                 float* __restrict__ istd) {
  const int j0 = blockIdx.x * 64;
  const int t = threadIdx.x;
  const int lane = t & 63, wv = t >> 6;
  const int c8 = t & 7, rr = t >> 3;
  float s[8] = {}, ss[8] = {};
  for (int r = rr; r < B_SZ * N_TOK; r += 32) {
    bf16x8 v = *(const bf16x8*)(hT + (long)r * 512 + j0 + c8 * 8);
#pragma unroll
    for (int e = 0; e < 8; ++e) {
      float f = (float)v[e];
      s[e] += f;
      ss[e] += f * f;
    }
  }
#pragma unroll
  for (int xm = 8; xm < 64; xm <<= 1)
#pragma unroll
    for (int e = 0; e < 8; ++e) {
      s[e] += __shfl_xor(s[e], xm);
      ss[e] += __shfl_xor(ss[e], xm);
    }
  __shared__ float red[2][4][64];
  if (lane < 8) {
#pragma unroll
    for (int e = 0; e < 8; ++e) {
      red[0][wv][lane * 8 + e] = s[e];
      red[1][wv][lane * 8 + e] = ss[e];
    }
  }
  __syncthreads();
  if (t < 64) {
    float su = red[0][0][t] + red[0][1][t] + red[0][2][t] + red[0][3][t];
    float sq = red[1][0][t] + red[1][1][t] + red[1][2][t] + red[1][3][t];
    const float invn = 1.f / (float)(B_SZ * N_TOK);
    float mu = su * invn;
    float var = sq * invn - mu * mu;
    mean[j0 + t] = mu;
    istd[j0 + t] = rsqrtf(var + 1e-3f);
  }
}

__global__ void bn_norm2(bf16* __restrict__ hT, const float* __restrict__ mean,
                         const float* __restrict__ istd, const float* __restrict__ gamma,
                         const float* __restrict__ beta) {
  long i = ((long)blockIdx.x * 256 + threadIdx.x) * 8;
  int c = (int)(i & 511);
  bf16x8 v = *(bf16x8*)(hT + i);
#pragma unroll
  for (int e = 0; e < 8; ++e) {
    int cc = c + e;
    float f = ((float)v[e] - mean[cc]) * istd[cc] * gamma[cc] + beta[cc];
    v[e] = (bf16)fmaxf(f, 0.f);
  }
  *(bf16x8*)(hT + i) = v;
}

extern "C" void kernel_launch(void* const* d_in, const int* in_sizes, int n_in,
                              void* d_out, int out_size, void* d_ws, size_t ws_size,
                              hipStream_t stream) {
  (void)in_sizes; (void)n_in; (void)out_size; (void)ws_size;
  const float* x = (const float*)d_in[0];
  const float* source = (const float*)d_in[1];
  const float* Wq = (const float*)d_in[2];
  const float* bq = (const float*)d_in[3];
  const float* Wk = (const float*)d_in[4];
  const float* bk = (const float*)d_in[5];
  const float* Wv = (const float*)d_in[6];
  const float* bv = (const float*)d_in[7];
  const float* Wm = (const float*)d_in[8];
  const float* bm = (const float*)d_in[9];
  const float* W1 = (const float*)d_in[10];
  const float* b1 = (const float*)d_in[11];
  const float* gamma1 = (const float*)d_in[12];
  const float* beta1 = (const float*)d_in[13];
  const float* W2 = (const float*)d_in[14];
  const float* b2 = (const float*)d_in[15];
  float* out = (float*)d_out;

  char* p = (char*)d_ws;
  size_t off = 0;
  auto alloc = [&](size_t bytes) {
    void* r = p + off;
    off += (bytes + 255) & ~(size_t)255;
    return r;
  };
  const long feat = (long)B_SZ * 256 * N_TOK;  // 4,194,304
  bf16* xT = (bf16*)alloc(feat * 2);
  bf16* sT = (bf16*)alloc(feat * 2);
  bf16* qT = (bf16*)alloc(feat * 2);
  bf16* kT = (bf16*)alloc(feat * 2);
  bf16* Vp = (bf16*)alloc(feat * 2);
  bf16* aT = (bf16*)alloc(feat * 2);
  bf16* mT = (bf16*)alloc(feat * 2);
  bf16* hT = (bf16*)alloc(feat * 4);  // [16384][512]
  bf16* Wqp = (bf16*)alloc(65536 * 2);
  bf16* Wkp = (bf16*)alloc(65536 * 2);
  bf16* Wvp = (bf16*)alloc(65536 * 2);
  bf16* Wmp = (bf16*)alloc(65536 * 2);
  bf16* W1b = (bf16*)alloc(262144 * 2);
  bf16* W2b = (bf16*)alloc(131072 * 2);
  float* bqp = (float*)alloc(256 * 4);
  float* bkp = (float*)alloc(256 * 4);
  float* bvp = (float*)alloc(256 * 4);
  float* mean = (float*)alloc(512 * 4);
  float* istd = (float*)alloc(512 * 4);

  dim3 blk(256);
  transpose_cvt<<<dim3(32, 4, 8), blk, 0, stream>>>(x, xT);
  transpose_cvt<<<dim3(32, 4, 8), blk, 0, stream>>>(source, sT);
  prep_kernel<<<1794, blk, 0, stream>>>(Wq, Wk, Wv, Wm, W1, W2, bq, bk, bv,
                                        Wqp, Wkp, Wvp, Wmp, W1b, W2b, bqp, bkp, bvp);

  const long bAct = (long)N_TOK * 256;  // activation batch stride (elems)
  // q/k projections: C[n][c'] token-major
  gemm_tn<<<dim3(4, 32, 8), blk, 0, stream>>>(xT, nullptr, 256, bAct, Wqp, 0, bqp, 1,
                                              qT, 0, 256, bAct, 256);
  gemm_tn<<<dim3(4, 32, 8), blk, 0, stream>>>(sT, nullptr, 256, bAct, Wkp, 0, bkp, 1,
                                              kT, 0, 256, bAct, 256);
  // v projection: C[c'][m] channel-major
  gemm_tn<<<dim3(32, 4, 8), blk, 0, stream>>>(Wvp, nullptr, 256, 0, sT, bAct, bvp, 0,
                                              Vp, 0, N_TOK, bAct, 256);

  attn2_kernel<<<dim3(32, 4, 8), blk, 0, stream>>>(qT, kT, Vp, aT);

  // message projection: C[n][m] token-major
  gemm_tn<<<dim3(4, 32, 8), blk, 0, stream>>>(aT, nullptr, 256, bAct, Wmp, 0, bm, 1,
                                              mT, 0, 256, bAct, 256);
  // MLP1 on concat([xT, mT]) along k: C[n][512] token-major
  gemm_tn<<<dim3(8, 32, 8), blk, 0, stream>>>(xT, mT, 256, bAct, W1b, 0, b1, 1,
                                              hT, 0, 512, (long)N_TOK * 512, 512);

  bn_stats2<<<8, blk, 0, stream>>>(hT, mean, istd);
  bn_norm2<<<4096, blk, 0, stream>>>(hT, mean, istd, gamma1, beta1);

  // MLP2: C[mch][n] channel-major fp32 -> d_out
  gemm_tn<<<dim3(32, 4, 8), blk, 0, stream>>>(W2b, nullptr, 512, 0, hT, (long)N_TOK * 512,
                                              b2, 0, out, 1, N_TOK, (long)256 * N_TOK, 512);
}

// Round 3
// 331.930 us; speedup vs baseline: 1.4741x; 1.4130x over previous
//
#include <hip/hip_runtime.h>
#include <hip/hip_bf16.h>
#include <math.h>

typedef __bf16 bf16;
typedef __bf16 bf16x4 __attribute__((ext_vector_type(4)));
typedef __bf16 bf16x8 __attribute__((ext_vector_type(8)));
typedef float f32x4 __attribute__((ext_vector_type(4)));

static constexpr int N_TOK = 2048;
static constexpr int B_SZ = 8;

#define MFMA(a, b, c) __builtin_amdgcn_mfma_f32_16x16x32_bf16((a), (b), (c), 0, 0, 0)

// A/B operand fragment from a k-contiguous row: elem j -> k = 16*(j>>2) + ((lane>>4)<<2) + (j&3)
__device__ __forceinline__ bf16x8 load_frag(const bf16* rowp, int lane) {
  const int g = (lane >> 4) << 2;
  bf16x4 lo = *(const bf16x4*)(rowp + g);
  bf16x4 hi = *(const bf16x4*)(rowp + g + 16);
  return __builtin_shufflevector(lo, hi, 0, 1, 2, 3, 4, 5, 6, 7);
}

// ---------------- transpose + convert: [b][256][2048] f32 -> [b][2048][256] bf16 ----------------
__global__ __launch_bounds__(256) void transpose_cvt(const float* __restrict__ in,
                                                     bf16* __restrict__ outT) {
  const int n0 = blockIdx.x * 64, c0 = blockIdx.y * 64, b = blockIdx.z;
  const int t = threadIdx.x;
  __shared__ bf16 T[64][72];
  {
    int c = t >> 2, nc = (t & 3) * 16;
    const float* src = in + ((long)b * 256 + c0 + c) * N_TOK + n0 + nc;
#pragma unroll
    for (int q = 0; q < 4; ++q) {
      float4 v = *(const float4*)(src + q * 4);
      T[c][nc + q * 4 + 0] = (bf16)v.x;
      T[c][nc + q * 4 + 1] = (bf16)v.y;
      T[c][nc + q * 4 + 2] = (bf16)v.z;
      T[c][nc + q * 4 + 3] = (bf16)v.w;
    }
  }
  __syncthreads();
  {
    int n = t >> 2, cc = (t & 3) * 16;
    bf16x8 o0, o1;
#pragma unroll
    for (int j = 0; j < 8; ++j) { o0[j] = T[cc + j][n]; o1[j] = T[cc + 8 + j][n]; }
    bf16* dst = outT + ((long)b * N_TOK + n0 + n) * 256 + c0 + cc;
    *(bf16x8*)dst = o0;
    *(bf16x8*)(dst + 8) = o1;
  }
}

// ---------------- weight prep: convert + head permutation ----------------
// perm(c') = (c'&63)*4 + (c'>>6)   (c' = h*64+d  <->  c = d*4+h)
__global__ void prep_kernel(const float* __restrict__ Wq, const float* __restrict__ Wk,
                            const float* __restrict__ Wv, const float* __restrict__ Wm,
                            const float* __restrict__ W1, const float* __restrict__ W2,
                            const float* __restrict__ bq, const float* __restrict__ bk,
                            const float* __restrict__ bv,
                            bf16* __restrict__ Wqp, bf16* __restrict__ Wkp,
                            bf16* __restrict__ Wvp, bf16* __restrict__ Wmp,
                            bf16* __restrict__ W1b, bf16* __restrict__ W2b,
                            float* __restrict__ bqp, float* __restrict__ bkp,
                            float* __restrict__ bvp) {
  int i = blockIdx.x * 256 + threadIdx.x;
  if (i < 65536) {
    int cp = i >> 8, k = i & 255;
    int src = (((cp & 63) << 2) | (cp >> 6)) * 256 + k;
    Wqp[i] = (bf16)Wq[src];
    Wkp[i] = (bf16)Wk[src];
    Wvp[i] = (bf16)Wv[src];
    int m = i >> 8, c2 = i & 255;
    Wmp[i] = (bf16)Wm[m * 256 + (((c2 & 63) << 2) | (c2 >> 6))];
  } else if (i < 65536 + 262144) {
    int j = i - 65536;
    W1b[j] = (bf16)W1[j];
  } else if (i < 65536 + 262144 + 131072) {
    int j = i - 327680;
    W2b[j] = (bf16)W2[j];
  } else if (i < 65536 + 262144 + 131072 + 256) {
    int c2 = i - 458752;
    int src = (c2 & 63) * 4 + (c2 >> 6);
    bqp[c2] = bq[src];
    bkp[c2] = bk[src];
    bvp[c2] = bv[src];
  }
}

// ---------------- generic TN GEMM: C[i][j] = sum_k A[i][k] * B[j][k] + bias ----------------
__global__ __launch_bounds__(256) void gemm_tn(
    const bf16* __restrict__ A0, const bf16* __restrict__ A1, int cSplit, long batchA,
    const bf16* __restrict__ B, long batchB,
    const float* __restrict__ bias, int biasOnCol,
    void* __restrict__ outp, int outF32, long outR, long batchOut, int K) {
  const int j0 = blockIdx.x * 64;
  const int i0 = blockIdx.y * 64;
  const int b = blockIdx.z;
  const int t = threadIdx.x;
  const int lane = t & 63, w = t >> 6;
  const int wi = (w >> 1) * 32, wj = (w & 1) * 32;
  __shared__ bf16 As[64][40], Bs[64][40];
  f32x4 acc[2][2] = {};
  const int sr = t >> 2, sc = (t & 3) * 8;
  const bf16* A0b = A0 + (long)b * batchA;
  const bf16* A1b = A1 ? A1 + (long)b * batchA : nullptr;
  const bf16* Bb = B + (long)b * batchB;

  for (int k0 = 0; k0 < K; k0 += 32) {
    __syncthreads();
    int kk = k0 + sc;
    const bf16* asrc = (kk < cSplit) ? A0b + (long)(i0 + sr) * cSplit + kk
                                     : A1b + (long)(i0 + sr) * (K - cSplit) + (kk - cSplit);
    *(bf16x8*)&As[sr][sc] = *(const bf16x8*)asrc;
    *(bf16x8*)&Bs[sr][sc] = *(const bf16x8*)(Bb + (long)(j0 + sr) * K + kk);
    __syncthreads();
    bf16x8 a0 = load_frag(&As[wi + (lane & 15)][0], lane);
    bf16x8 a1 = load_frag(&As[wi + 16 + (lane & 15)][0], lane);
    bf16x8 b0 = load_frag(&Bs[wj + (lane & 15)][0], lane);
    bf16x8 b1 = load_frag(&Bs[wj + 16 + (lane & 15)][0], lane);
    acc[0][0] = MFMA(a0, b0, acc[0][0]);
    acc[0][1] = MFMA(a0, b1, acc[0][1]);
    acc[1][0] = MFMA(a1, b0, acc[1][0]);
    acc[1][1] = MFMA(a1, b1, acc[1][1]);
  }

  float* outf = (float*)outp;
  bf16* outb = (bf16*)outp;
  const int g4 = (lane >> 4) << 2;
#pragma unroll
  for (int fm = 0; fm < 2; ++fm)
#pragma unroll
    for (int fn = 0; fn < 2; ++fn)
#pragma unroll
      for (int r = 0; r < 4; ++r) {
        int i = i0 + wi + fm * 16 + g4 + r;
        int j = j0 + wj + fn * 16 + (lane & 15);
        float v = acc[fm][fn][r] + (bias ? bias[biasOnCol ? j : i] : 0.f);
        long idx = (long)b * batchOut + (long)i * outR + j;
        if (outF32) outf[idx] = v;
        else outb[idx] = (bf16)v;
      }
}

// ---------------- flash attention v2 (all operands k-contiguous) ----------------
__global__ __launch_bounds__(256) void attn2_kernel(
    const bf16* __restrict__ qT, const bf16* __restrict__ kT,
    const bf16* __restrict__ Vp, bf16* __restrict__ aT) {
  const int n0 = blockIdx.x * 64;
  const int h = blockIdx.y, b = blockIdx.z;
  const int t = threadIdx.x, lane = t & 63, w = t >> 6;
  const int g4 = (lane >> 4) << 2;
  __shared__ bf16 Qs[64][72], Ks[64][72], Vs[64][72], Ps[64][72];
  const int sr = t >> 2, sc = (t & 3) * 16;
  const float SCL = 0.125f * 1.44269504088896340736f;  // 1/sqrt(64) * log2(e)

  {  // stage Q (scaled)
    const bf16* src = qT + ((long)(b * N_TOK + n0 + sr)) * 256 + h * 64 + sc;
    bf16x8 v0 = *(const bf16x8*)src, v1 = *(const bf16x8*)(src + 8);
#pragma unroll
    for (int j = 0; j < 8; ++j) {
      Qs[sr][sc + j] = (bf16)((float)v0[j] * SCL);
      Qs[sr][sc + 8 + j] = (bf16)((float)v1[j] * SCL);
    }
  }

  float m_r[4], l_r[4];
  f32x4 o[4] = {};
#pragma unroll
  for (int r = 0; r < 4; ++r) { m_r[r] = -INFINITY; l_r[r] = 0.f; }

  for (int mt = 0; mt < 32; ++mt) {
    const int m0 = mt * 64;
    __syncthreads();
    {  // stage K tile [64m][64d]
      const bf16* src = kT + ((long)(b * N_TOK + m0 + sr)) * 256 + h * 64 + sc;
      *(bf16x8*)&Ks[sr][sc] = *(const bf16x8*)src;
      *(bf16x8*)&Ks[sr][sc + 8] = *(const bf16x8*)(src + 8);
    }
    {  // stage V tile [64d][64m]
      const bf16* src = Vp + ((long)(b * 256 + h * 64 + sr)) * N_TOK + m0 + sc;
      *(bf16x8*)&Vs[sr][sc] = *(const bf16x8*)src;
      *(bf16x8*)&Vs[sr][sc + 8] = *(const bf16x8*)(src + 8);
    }
    __syncthreads();

    f32x4 s[4];
#pragma unroll
    for (int f = 0; f < 4; ++f) {
      s[f] = (f32x4){0.f, 0.f, 0.f, 0.f};
#pragma unroll
      for (int ks = 0; ks < 2; ++ks) {
        bf16x8 a = load_frag(&Qs[16 * w + (lane & 15)][ks * 32], lane);
        bf16x8 bb = load_frag(&Ks[16 * f + (lane & 15)][ks * 32], lane);
        s[f] = MFMA(a, bb, s[f]);
      }
    }

    float mx[4];
#pragma unroll
    for (int r = 0; r < 4; ++r)
      mx[r] = fmaxf(fmaxf(s[0][r], s[1][r]), fmaxf(s[2][r], s[3][r]));
#pragma unroll
    for (int xm = 1; xm <= 8; xm <<= 1)
#pragma unroll
      for (int r = 0; r < 4; ++r) mx[r] = fmaxf(mx[r], __shfl_xor(mx[r], xm));

    float fac[4], rs[4] = {0.f, 0.f, 0.f, 0.f};
#pragma unroll
    for (int r = 0; r < 4; ++r) {
      float mn = fmaxf(m_r[r], mx[r]);
      fac[r] = exp2f(m_r[r] - mn);
      m_r[r] = mn;
    }
#pragma unroll
    for (int f = 0; f < 4; ++f)
#pragma unroll
      for (int r = 0; r < 4; ++r) {
        float p = exp2f(s[f][r] - m_r[r]);
        rs[r] += p;
        Ps[16 * w + g4 + r][16 * f + (lane & 15)] = (bf16)p;
      }
#pragma unroll
    for (int xm = 1; xm <= 8; xm <<= 1)
#pragma unroll
      for (int r = 0; r < 4; ++r) rs[r] += __shfl_xor(rs[r], xm);
#pragma unroll
    for (int r = 0; r < 4; ++r) l_r[r] = l_r[r] * fac[r] + rs[r];
#pragma unroll
    for (int f2 = 0; f2 < 4; ++f2)
#pragma unroll
      for (int r = 0; r < 4; ++r) o[f2][r] *= fac[r];
    __syncthreads();

#pragma unroll
    for (int f2 = 0; f2 < 4; ++f2)
#pragma unroll
      for (int ks = 0; ks < 2; ++ks) {
        bf16x8 a = load_frag(&Ps[16 * w + (lane & 15)][ks * 32], lane);
        bf16x8 bb = load_frag(&Vs[16 * f2 + (lane & 15)][ks * 32], lane);
        o[f2] = MFMA(a, bb, o[f2]);
      }
  }

  float inv[4];
#pragma unroll
  for (int r = 0; r < 4; ++r) inv[r] = 1.f / l_r[r];
#pragma unroll
  for (int f2 = 0; f2 < 4; ++f2)
#pragma unroll
    for (int r = 0; r < 4; ++r) {
      int n = n0 + 16 * w + g4 + r;
      int d = 16 * f2 + (lane & 15);
      aT[((long)(b * N_TOK + n)) * 256 + h * 64 + d] = (bf16)(o[f2][r] * inv[r]);
    }
}

// ---------------- BatchNorm stats: two-stage deterministic reduction ----------------
// Stage A: 512 blocks, 32 rows each of hT [16384][512] -> partial sums [512][512]
__global__ __launch_bounds__(256) void bn_partial(const bf16* __restrict__ hT,
                                                  float* __restrict__ ps,
                                                  float* __restrict__ pss) {
  const int g = blockIdx.x;
  const int t = threadIdx.x;
  const int cg = (t & 63) * 8;
  const int w = t >> 6;
  float s[8] = {}, ss[8] = {};
  const int rend = g * 32 + 32;
  for (int r = g * 32 + w; r < rend; r += 4) {
    bf16x8 v = *(const bf16x8*)(hT + (long)r * 512 + cg);
#pragma unroll
    for (int e = 0; e < 8; ++e) {
      float f = (float)v[e];
      s[e] += f;
      ss[e] += f * f;
    }
  }
  __shared__ float red[2][4][512];
#pragma unroll
  for (int e = 0; e < 8; ++e) {
    red[0][w][cg + e] = s[e];
    red[1][w][cg + e] = ss[e];
  }
  __syncthreads();
#pragma unroll
  for (int q = 0; q < 2; ++q) {
    int c = t * 2 + q;
    ps[(long)g * 512 + c] = red[0][0][c] + red[0][1][c] + red[0][2][c] + red[0][3][c];
    pss[(long)g * 512 + c] = red[1][0][c] + red[1][1][c] + red[1][2][c] + red[1][3][c];
  }
}

// Stage B: 8 blocks x 64 channels; reduce 512 partials per channel
__global__ __launch_bounds__(256) void bn_finalize(const float* __restrict__ ps,
                                                   const float* __restrict__ pss,
                                                   float* __restrict__ mean,
                                                   float* __restrict__ istd) {
  const int j0 = blockIdx.x * 64;
  const int t = threadIdx.x;
  const int c = j0 + (t & 63);
  const int w = t >> 6;
  float s = 0.f, ss = 0.f;
  for (int g = w; g < 512; g += 4) {
    s += ps[(long)g * 512 + c];
    ss += pss[(long)g * 512 + c];
  }
  __shared__ float red[2][4][64];
  red[0][w][t & 63] = s;
  red[1][w][t & 63] = ss;
  __syncthreads();
  if (t < 64) {
    float su = red[0][0][t] + red[0][1][t] + red[0][2][t] + red[0][3][t];
    float sq = red[1][0][t] + red[1][1][t] + red[1][2][t] + red[1][3][t];
    const float invn = 1.f / (float)(B_SZ * N_TOK);
    float mu = su * invn;
    float var = sq * invn - mu * mu;
    mean[j0 + t] = mu;
    istd[j0 + t] = rsqrtf(var + 1e-3f);
  }
}

__global__ void bn_norm2(bf16* __restrict__ hT, const float* __restrict__ mean,
                         const float* __restrict__ istd, const float* __restrict__ gamma,
                         const float* __restrict__ beta) {
  long i = ((long)blockIdx.x * 256 + threadIdx.x) * 8;
  int c = (int)(i & 511);
  bf16x8 v = *(bf16x8*)(hT + i);
#pragma unroll
  for (int e = 0; e < 8; ++e) {
    int cc = c + e;
    float f = ((float)v[e] - mean[cc]) * istd[cc] * gamma[cc] + beta[cc];
    v[e] = (bf16)fmaxf(f, 0.f);
  }
  *(bf16x8*)(hT + i) = v;
}

extern "C" void kernel_launch(void* const* d_in, const int* in_sizes, int n_in,
                              void* d_out, int out_size, void* d_ws, size_t ws_size,
                              hipStream_t stream) {
  (void)in_sizes; (void)n_in; (void)out_size; (void)ws_size;
  const float* x = (const float*)d_in[0];
  const float* source = (const float*)d_in[1];
  const float* Wq = (const float*)d_in[2];
  const float* bq = (const float*)d_in[3];
  const float* Wk = (const float*)d_in[4];
  const float* bk = (const float*)d_in[5];
  const float* Wv = (const float*)d_in[6];
  const float* bv = (const float*)d_in[7];
  const float* Wm = (const float*)d_in[8];
  const float* bm = (const float*)d_in[9];
  const float* W1 = (const float*)d_in[10];
  const float* b1 = (const float*)d_in[11];
  const float* gamma1 = (const float*)d_in[12];
  const float* beta1 = (const float*)d_in[13];
  const float* W2 = (const float*)d_in[14];
  const float* b2 = (const float*)d_in[15];
  float* out = (float*)d_out;

  char* p = (char*)d_ws;
  size_t off = 0;
  auto alloc = [&](size_t bytes) {
    void* r = p + off;
    off += (bytes + 255) & ~(size_t)255;
    return r;
  };
  const long feat = (long)B_SZ * 256 * N_TOK;  // 4,194,304
  bf16* xT = (bf16*)alloc(feat * 2);
  bf16* sT = (bf16*)alloc(feat * 2);
  bf16* qT = (bf16*)alloc(feat * 2);
  bf16* kT = (bf16*)alloc(feat * 2);
  bf16* Vp = (bf16*)alloc(feat * 2);
  bf16* aT = (bf16*)alloc(feat * 2);
  bf16* mT = (bf16*)alloc(feat * 2);
  bf16* hT = (bf16*)alloc(feat * 4);  // [16384][512]
  bf16* Wqp = (bf16*)alloc(65536 * 2);
  bf16* Wkp = (bf16*)alloc(65536 * 2);
  bf16* Wvp = (bf16*)alloc(65536 * 2);
  bf16* Wmp = (bf16*)alloc(65536 * 2);
  bf16* W1b = (bf16*)alloc(262144 * 2);
  bf16* W2b = (bf16*)alloc(131072 * 2);
  float* bqp = (float*)alloc(256 * 4);
  float* bkp = (float*)alloc(256 * 4);
  float* bvp = (float*)alloc(256 * 4);
  float* mean = (float*)alloc(512 * 4);
  float* istd = (float*)alloc(512 * 4);
  float* ps = (float*)alloc(512 * 512 * 4);
  float* pss = (float*)alloc(512 * 512 * 4);

  dim3 blk(256);
  transpose_cvt<<<dim3(32, 4, 8), blk, 0, stream>>>(x, xT);
  transpose_cvt<<<dim3(32, 4, 8), blk, 0, stream>>>(source, sT);
  prep_kernel<<<1794, blk, 0, stream>>>(Wq, Wk, Wv, Wm, W1, W2, bq, bk, bv,
                                        Wqp, Wkp, Wvp, Wmp, W1b, W2b, bqp, bkp, bvp);

  const long bAct = (long)N_TOK * 256;
  gemm_tn<<<dim3(4, 32, 8), blk, 0, stream>>>(xT, nullptr, 256, bAct, Wqp, 0, bqp, 1,
                                              qT, 0, 256, bAct, 256);
  gemm_tn<<<dim3(4, 32, 8), blk, 0, stream>>>(sT, nullptr, 256, bAct, Wkp, 0, bkp, 1,
                                              kT, 0, 256, bAct, 256);
  gemm_tn<<<dim3(32, 4, 8), blk, 0, stream>>>(Wvp, nullptr, 256, 0, sT, bAct, bvp, 0,
                                              Vp, 0, N_TOK, bAct, 256);

  attn2_kernel<<<dim3(32, 4, 8), blk, 0, stream>>>(qT, kT, Vp, aT);

  gemm_tn<<<dim3(4, 32, 8), blk, 0, stream>>>(aT, nullptr, 256, bAct, Wmp, 0, bm, 1,
                                              mT, 0, 256, bAct, 256);
  gemm_tn<<<dim3(8, 32, 8), blk, 0, stream>>>(xT, mT, 256, bAct, W1b, 0, b1, 1,
                                              hT, 0, 512, (long)N_TOK * 512, 512);

  bn_partial<<<512, blk, 0, stream>>>(hT, ps, pss);
  bn_finalize<<<8, blk, 0, stream>>>(ps, pss, mean, istd);
  bn_norm2<<<4096, blk, 0, stream>>>(hT, mean, istd, gamma1, beta1);

  gemm_tn<<<dim3(32, 4, 8), blk, 0, stream>>>(W2b, nullptr, 512, 0, hT, (long)N_TOK * 512,
                                              b2, 0, out, 1, N_TOK, (long)256 * N_TOK, 512);
}

// Round 4
// 265.622 us; speedup vs baseline: 1.8421x; 1.2496x over previous
//
#include <hip/hip_runtime.h>
#include <hip/hip_bf16.h>
#include <math.h>

typedef __bf16 bf16;
typedef __bf16 bf16x4 __attribute__((ext_vector_type(4)));
typedef __bf16 bf16x8 __attribute__((ext_vector_type(8)));
typedef float f32x4 __attribute__((ext_vector_type(4)));

static constexpr int N_TOK = 2048;
static constexpr int B_SZ = 8;

#define MFMA(a, b, c) __builtin_amdgcn_mfma_f32_16x16x32_bf16((a), (b), (c), 0, 0, 0)

// A/B operand fragment from a k-contiguous row: elem j -> k = 16*(j>>2) + ((lane>>4)<<2) + (j&3)
__device__ __forceinline__ bf16x8 load_frag(const bf16* rowp, int lane) {
  const int g = (lane >> 4) << 2;
  bf16x4 lo = *(const bf16x4*)(rowp + g);
  bf16x4 hi = *(const bf16x4*)(rowp + g + 16);
  return __builtin_shufflevector(lo, hi, 0, 1, 2, 3, 4, 5, 6, 7);
}

// ---------------- transpose + convert: [b][256][2048] f32 -> [b][2048][256] bf16 ----------------
__global__ __launch_bounds__(256) void transpose_cvt(const float* __restrict__ in,
                                                     bf16* __restrict__ outT) {
  const int n0 = blockIdx.x * 64, c0 = blockIdx.y * 64, b = blockIdx.z;
  const int t = threadIdx.x;
  __shared__ bf16 T[64][72];
  {
    int c = t >> 2, nc = (t & 3) * 16;
    const float* src = in + ((long)b * 256 + c0 + c) * N_TOK + n0 + nc;
#pragma unroll
    for (int q = 0; q < 4; ++q) {
      float4 v = *(const float4*)(src + q * 4);
      T[c][nc + q * 4 + 0] = (bf16)v.x;
      T[c][nc + q * 4 + 1] = (bf16)v.y;
      T[c][nc + q * 4 + 2] = (bf16)v.z;
      T[c][nc + q * 4 + 3] = (bf16)v.w;
    }
  }
  __syncthreads();
  {
    int n = t >> 2, cc = (t & 3) * 16;
    bf16x8 o0, o1;
#pragma unroll
    for (int j = 0; j < 8; ++j) { o0[j] = T[cc + j][n]; o1[j] = T[cc + 8 + j][n]; }
    bf16* dst = outT + ((long)b * N_TOK + n0 + n) * 256 + c0 + cc;
    *(bf16x8*)dst = o0;
    *(bf16x8*)(dst + 8) = o1;
  }
}

// ---------------- weight prep: convert + head permutation ----------------
// perm(c') = (c'&63)*4 + (c'>>6)   (c' = h*64+d  <->  c = d*4+h)
__global__ void prep_kernel(const float* __restrict__ Wq, const float* __restrict__ Wk,
                            const float* __restrict__ Wv, const float* __restrict__ Wm,
                            const float* __restrict__ W1, const float* __restrict__ W2,
                            const float* __restrict__ bq, const float* __restrict__ bk,
                            const float* __restrict__ bv,
                            bf16* __restrict__ Wqp, bf16* __restrict__ Wkp,
                            bf16* __restrict__ Wvp, bf16* __restrict__ Wmp,
                            bf16* __restrict__ W1b, bf16* __restrict__ W2b,
                            float* __restrict__ bqp, float* __restrict__ bkp,
                            float* __restrict__ bvp) {
  int i = blockIdx.x * 256 + threadIdx.x;
  if (i < 65536) {
    int cp = i >> 8, k = i & 255;
    int src = (((cp & 63) << 2) | (cp >> 6)) * 256 + k;
    Wqp[i] = (bf16)Wq[src];
    Wkp[i] = (bf16)Wk[src];
    Wvp[i] = (bf16)Wv[src];
    int m = i >> 8, c2 = i & 255;
    Wmp[i] = (bf16)Wm[m * 256 + (((c2 & 63) << 2) | (c2 >> 6))];
  } else if (i < 65536 + 262144) {
    int j = i - 65536;
    W1b[j] = (bf16)W1[j];
  } else if (i < 65536 + 262144 + 131072) {
    int j = i - 327680;
    W2b[j] = (bf16)W2[j];
  } else if (i < 65536 + 262144 + 131072 + 256) {
    int c2 = i - 458752;
    int src = (c2 & 63) * 4 + (c2 >> 6);
    bqp[c2] = bq[src];
    bkp[c2] = bk[src];
    bvp[c2] = bv[src];
  }
}

// ---------------- generic TN GEMM: C[i][j] = sum_k A[i][k] * B[j][k] + bias ----------------
__global__ __launch_bounds__(256) void gemm_tn(
    const bf16* __restrict__ A0, const bf16* __restrict__ A1, int cSplit, long batchA,
    const bf16* __restrict__ B, long batchB,
    const float* __restrict__ bias, int biasOnCol,
    void* __restrict__ outp, int outF32, long outR, long batchOut, int K) {
  const int j0 = blockIdx.x * 64;
  const int i0 = blockIdx.y * 64;
  const int b = blockIdx.z;
  const int t = threadIdx.x;
  const int lane = t & 63, w = t >> 6;
  const int wi = (w >> 1) * 32, wj = (w & 1) * 32;
  __shared__ bf16 As[64][40], Bs[64][40];
  f32x4 acc[2][2] = {};
  const int sr = t >> 2, sc = (t & 3) * 8;
  const bf16* A0b = A0 + (long)b * batchA;
  const bf16* A1b = A1 ? A1 + (long)b * batchA : nullptr;
  const bf16* Bb = B + (long)b * batchB;

  for (int k0 = 0; k0 < K; k0 += 32) {
    __syncthreads();
    int kk = k0 + sc;
    const bf16* asrc = (kk < cSplit) ? A0b + (long)(i0 + sr) * cSplit + kk
                                     : A1b + (long)(i0 + sr) * (K - cSplit) + (kk - cSplit);
    *(bf16x8*)&As[sr][sc] = *(const bf16x8*)asrc;
    *(bf16x8*)&Bs[sr][sc] = *(const bf16x8*)(Bb + (long)(j0 + sr) * K + kk);
    __syncthreads();
    bf16x8 a0 = load_frag(&As[wi + (lane & 15)][0], lane);
    bf16x8 a1 = load_frag(&As[wi + 16 + (lane & 15)][0], lane);
    bf16x8 b0 = load_frag(&Bs[wj + (lane & 15)][0], lane);
    bf16x8 b1 = load_frag(&Bs[wj + 16 + (lane & 15)][0], lane);
    acc[0][0] = MFMA(a0, b0, acc[0][0]);
    acc[0][1] = MFMA(a0, b1, acc[0][1]);
    acc[1][0] = MFMA(a1, b0, acc[1][0]);
    acc[1][1] = MFMA(a1, b1, acc[1][1]);
  }

  float* outf = (float*)outp;
  bf16* outb = (bf16*)outp;
  const int g4 = (lane >> 4) << 2;
#pragma unroll
  for (int fm = 0; fm < 2; ++fm)
#pragma unroll
    for (int fn = 0; fn < 2; ++fn)
#pragma unroll
      for (int r = 0; r < 4; ++r) {
        int i = i0 + wi + fm * 16 + g4 + r;
        int j = j0 + wj + fn * 16 + (lane & 15);
        float v = acc[fm][fn][r] + (bias ? bias[biasOnCol ? j : i] : 0.f);
        long idx = (long)b * batchOut + (long)i * outR + j;
        if (outF32) outf[idx] = v;
        else outb[idx] = (bf16)v;
      }
}

// ---------------- flash attention v3: swapped QK^T, lane-local softmax, no P LDS ----------------
// qT/kT: [b][n][c'=h*64+d] token-major ; Vp: [b][c'][m] channel-major ; out aT: [b][n][c']
__global__ __launch_bounds__(256) void attn3_kernel(
    const bf16* __restrict__ qT, const bf16* __restrict__ kT,
    const bf16* __restrict__ Vp, bf16* __restrict__ aT) {
  const int n0 = blockIdx.x * 64;
  const int h = blockIdx.y, b = blockIdx.z;
  const int t = threadIdx.x, lane = t & 63, w = t >> 6;
  const int nl = lane & 15;           // this lane's q-row (local to wave)
  const int g4 = (lane >> 4) << 2;
  __shared__ bf16 Ks[64][72], Vs[64][72];
  const int sr = t >> 2, sc = (t & 3) * 16;
  const float SCL = 0.125f * 1.44269504088896340736f;  // 1/sqrt(64) * log2(e)

  // Hoisted Q fragments (B operand, mt-invariant): row n = n0+16w+nl
  bf16x8 qf[2];
  {
    const bf16* qrow = qT + ((long)(b * N_TOK + n0 + 16 * w + nl)) * 256 + h * 64 + g4;
#pragma unroll
    for (int ks = 0; ks < 2; ++ks) {
      bf16x4 lo = *(const bf16x4*)(qrow + ks * 32);
      bf16x4 hi = *(const bf16x4*)(qrow + ks * 32 + 16);
      bf16x8 f = __builtin_shufflevector(lo, hi, 0, 1, 2, 3, 4, 5, 6, 7);
#pragma unroll
      for (int j = 0; j < 8; ++j) f[j] = (bf16)((float)f[j] * SCL);
      qf[ks] = f;
    }
  }

  float m_r = -INFINITY, l_r = 0.f;
  f32x4 o[4] = {};

  for (int mt = 0; mt < 32; ++mt) {
    const int m0 = mt * 64;
    __syncthreads();
    {  // stage K tile [64m][64d]
      const bf16* src = kT + ((long)(b * N_TOK + m0 + sr)) * 256 + h * 64 + sc;
      *(bf16x8*)&Ks[sr][sc] = *(const bf16x8*)src;
      *(bf16x8*)&Ks[sr][sc + 8] = *(const bf16x8*)(src + 8);
    }
    {  // stage V tile [64d][64m]
      const bf16* src = Vp + ((long)(b * 256 + h * 64 + sr)) * N_TOK + m0 + sc;
      *(bf16x8*)&Vs[sr][sc] = *(const bf16x8*)src;
      *(bf16x8*)&Vs[sr][sc + 8] = *(const bf16x8*)(src + 8);
    }
    __syncthreads();

    // St[m][n] = K · Q^T : lane holds St[16f+g4+r][16w+nl] for f,r in 0..3
    f32x4 s[4];
#pragma unroll
    for (int f = 0; f < 4; ++f) {
      s[f] = (f32x4){0.f, 0.f, 0.f, 0.f};
#pragma unroll
      for (int ks = 0; ks < 2; ++ks)
        s[f] = MFMA(load_frag(&Ks[16 * f + nl][ks * 32], lane), qf[ks], s[f]);
    }

    // lane-local softmax for q-row nl (m values replicated across lane groups)
    float mx = s[0][0];
#pragma unroll
    for (int f = 0; f < 4; ++f)
#pragma unroll
      for (int r = 0; r < 4; ++r) mx = fmaxf(mx, s[f][r]);
    mx = fmaxf(mx, __shfl_xor(mx, 16));
    mx = fmaxf(mx, __shfl_xor(mx, 32));

    float mn = fmaxf(m_r, mx);
    float fac = exp2f(m_r - mn);  // first tile: exp2(-inf)=0
    m_r = mn;

    bf16x8 pb[2];
    float rs = 0.f;
#pragma unroll
    for (int f = 0; f < 4; ++f)
#pragma unroll
      for (int r = 0; r < 4; ++r) {
        float pv = exp2f(s[f][r] - mn);
        rs += pv;
        pb[f >> 1][(f & 1) * 4 + r] = (bf16)pv;
      }
    rs += __shfl_xor(rs, 16);
    rs += __shfl_xor(rs, 32);
    l_r = l_r * fac + rs;

#pragma unroll
    for (int f2 = 0; f2 < 4; ++f2)
#pragma unroll
      for (int r = 0; r < 4; ++r) o[f2][r] *= fac;

    // O^T[d][n] += V · P : A = V rows d, B = P^T rows n (lane-local, no LDS)
#pragma unroll
    for (int f2 = 0; f2 < 4; ++f2)
#pragma unroll
      for (int ks = 0; ks < 2; ++ks)
        o[f2] = MFMA(load_frag(&Vs[16 * f2 + nl][ks * 32], lane), pb[ks], o[f2]);
  }

  // write O^T -> aT via per-wave LDS transpose (reuse Ks rows 16w..16w+15)
  __syncthreads();
  float inv = 1.f / l_r;
#pragma unroll
  for (int f2 = 0; f2 < 4; ++f2)
#pragma unroll
    for (int r = 0; r < 4; ++r)
      Ks[16 * w + nl][16 * f2 + g4 + r] = (bf16)(o[f2][r] * inv);
  __syncthreads();
  {
    int rr = lane >> 2, cc = (lane & 3) * 16;
    bf16x8 v0 = *(const bf16x8*)&Ks[16 * w + rr][cc];
    bf16x8 v1 = *(const bf16x8*)&Ks[16 * w + rr][cc + 8];
    bf16* dst = aT + ((long)(b * N_TOK + n0 + 16 * w + rr)) * 256 + h * 64 + cc;
    *(bf16x8*)dst = v0;
    *(bf16x8*)(dst + 8) = v1;
  }
}

// ---------------- BatchNorm stats: two-stage deterministic reduction ----------------
__global__ __launch_bounds__(256) void bn_partial(const bf16* __restrict__ hT,
                                                  float* __restrict__ ps,
                                                  float* __restrict__ pss) {
  const int g = blockIdx.x;
  const int t = threadIdx.x;
  const int cg = (t & 63) * 8;
  const int w = t >> 6;
  float s[8] = {}, ss[8] = {};
  const int rend = g * 32 + 32;
  for (int r = g * 32 + w; r < rend; r += 4) {
    bf16x8 v = *(const bf16x8*)(hT + (long)r * 512 + cg);
#pragma unroll
    for (int e = 0; e < 8; ++e) {
      float f = (float)v[e];
      s[e] += f;
      ss[e] += f * f;
    }
  }
  __shared__ float red[2][4][512];
#pragma unroll
  for (int e = 0; e < 8; ++e) {
    red[0][w][cg + e] = s[e];
    red[1][w][cg + e] = ss[e];
  }
  __syncthreads();
#pragma unroll
  for (int q = 0; q < 2; ++q) {
    int c = t * 2 + q;
    ps[(long)g * 512 + c] = red[0][0][c] + red[0][1][c] + red[0][2][c] + red[0][3][c];
    pss[(long)g * 512 + c] = red[1][0][c] + red[1][1][c] + red[1][2][c] + red[1][3][c];
  }
}

__global__ __launch_bounds__(256) void bn_finalize(const float* __restrict__ ps,
                                                   const float* __restrict__ pss,
                                                   float* __restrict__ mean,
                                                   float* __restrict__ istd) {
  const int j0 = blockIdx.x * 64;
  const int t = threadIdx.x;
  const int c = j0 + (t & 63);
  const int w = t >> 6;
  float s = 0.f, ss = 0.f;
  for (int g = w; g < 512; g += 4) {
    s += ps[(long)g * 512 + c];
    ss += pss[(long)g * 512 + c];
  }
  __shared__ float red[2][4][64];
  red[0][w][t & 63] = s;
  red[1][w][t & 63] = ss;
  __syncthreads();
  if (t < 64) {
    float su = red[0][0][t] + red[0][1][t] + red[0][2][t] + red[0][3][t];
    float sq = red[1][0][t] + red[1][1][t] + red[1][2][t] + red[1][3][t];
    const float invn = 1.f / (float)(B_SZ * N_TOK);
    float mu = su * invn;
    float var = sq * invn - mu * mu;
    mean[j0 + t] = mu;
    istd[j0 + t] = rsqrtf(var + 1e-3f);
  }
}

__global__ void bn_norm2(bf16* __restrict__ hT, const float* __restrict__ mean,
                         const float* __restrict__ istd, const float* __restrict__ gamma,
                         const float* __restrict__ beta) {
  long i = ((long)blockIdx.x * 256 + threadIdx.x) * 8;
  int c = (int)(i & 511);
  bf16x8 v = *(bf16x8*)(hT + i);
#pragma unroll
  for (int e = 0; e < 8; ++e) {
    int cc = c + e;
    float f = ((float)v[e] - mean[cc]) * istd[cc] * gamma[cc] + beta[cc];
    v[e] = (bf16)fmaxf(f, 0.f);
  }
  *(bf16x8*)(hT + i) = v;
}

extern "C" void kernel_launch(void* const* d_in, const int* in_sizes, int n_in,
                              void* d_out, int out_size, void* d_ws, size_t ws_size,
                              hipStream_t stream) {
  (void)in_sizes; (void)n_in; (void)out_size; (void)ws_size;
  const float* x = (const float*)d_in[0];
  const float* source = (const float*)d_in[1];
  const float* Wq = (const float*)d_in[2];
  const float* bq = (const float*)d_in[3];
  const float* Wk = (const float*)d_in[4];
  const float* bk = (const float*)d_in[5];
  const float* Wv = (const float*)d_in[6];
  const float* bv = (const float*)d_in[7];
  const float* Wm = (const float*)d_in[8];
  const float* bm = (const float*)d_in[9];
  const float* W1 = (const float*)d_in[10];
  const float* b1 = (const float*)d_in[11];
  const float* gamma1 = (const float*)d_in[12];
  const float* beta1 = (const float*)d_in[13];
  const float* W2 = (const float*)d_in[14];
  const float* b2 = (const float*)d_in[15];
  float* out = (float*)d_out;

  char* p = (char*)d_ws;
  size_t off = 0;
  auto alloc = [&](size_t bytes) {
    void* r = p + off;
    off += (bytes + 255) & ~(size_t)255;
    return r;
  };
  const long feat = (long)B_SZ * 256 * N_TOK;  // 4,194,304
  bf16* xT = (bf16*)alloc(feat * 2);
  bf16* sT = (bf16*)alloc(feat * 2);
  bf16* qT = (bf16*)alloc(feat * 2);
  bf16* kT = (bf16*)alloc(feat * 2);
  bf16* Vp = (bf16*)alloc(feat * 2);
  bf16* aT = (bf16*)alloc(feat * 2);
  bf16* mT = (bf16*)alloc(feat * 2);
  bf16* hT = (bf16*)alloc(feat * 4);  // [16384][512]
  bf16* Wqp = (bf16*)alloc(65536 * 2);
  bf16* Wkp = (bf16*)alloc(65536 * 2);
  bf16* Wvp = (bf16*)alloc(65536 * 2);
  bf16* Wmp = (bf16*)alloc(65536 * 2);
  bf16* W1b = (bf16*)alloc(262144 * 2);
  bf16* W2b = (bf16*)alloc(131072 * 2);
  float* bqp = (float*)alloc(256 * 4);
  float* bkp = (float*)alloc(256 * 4);
  float* bvp = (float*)alloc(256 * 4);
  float* mean = (float*)alloc(512 * 4);
  float* istd = (float*)alloc(512 * 4);
  float* ps = (float*)alloc(512 * 512 * 4);
  float* pss = (float*)alloc(512 * 512 * 4);

  dim3 blk(256);
  transpose_cvt<<<dim3(32, 4, 8), blk, 0, stream>>>(x, xT);
  transpose_cvt<<<dim3(32, 4, 8), blk, 0, stream>>>(source, sT);
  prep_kernel<<<1794, blk, 0, stream>>>(Wq, Wk, Wv, Wm, W1, W2, bq, bk, bv,
                                        Wqp, Wkp, Wvp, Wmp, W1b, W2b, bqp, bkp, bvp);

  const long bAct = (long)N_TOK * 256;
  gemm_tn<<<dim3(4, 32, 8), blk, 0, stream>>>(xT, nullptr, 256, bAct, Wqp, 0, bqp, 1,
                                              qT, 0, 256, bAct, 256);
  gemm_tn<<<dim3(4, 32, 8), blk, 0, stream>>>(sT, nullptr, 256, bAct, Wkp, 0, bkp, 1,
                                              kT, 0, 256, bAct, 256);
  gemm_tn<<<dim3(32, 4, 8), blk, 0, stream>>>(Wvp, nullptr, 256, 0, sT, bAct, bvp, 0,
                                              Vp, 0, N_TOK, bAct, 256);

  attn3_kernel<<<dim3(32, 4, 8), blk, 0, stream>>>(qT, kT, Vp, aT);

  gemm_tn<<<dim3(4, 32, 8), blk, 0, stream>>>(aT, nullptr, 256, bAct, Wmp, 0, bm, 1,
                                              mT, 0, 256, bAct, 256);
  gemm_tn<<<dim3(8, 32, 8), blk, 0, stream>>>(xT, mT, 256, bAct, W1b, 0, b1, 1,
                                              hT, 0, 512, (long)N_TOK * 512, 512);

  bn_partial<<<512, blk, 0, stream>>>(hT, ps, pss);
  bn_finalize<<<8, blk, 0, stream>>>(ps, pss, mean, istd);
  bn_norm2<<<4096, blk, 0, stream>>>(hT, mean, istd, gamma1, beta1);

  gemm_tn<<<dim3(32, 4, 8), blk, 0, stream>>>(W2b, nullptr, 512, 0, hT, (long)N_TOK * 512,
                                              b2, 0, out, 1, N_TOK, (long)256 * N_TOK, 512);
}

// Round 5
// 246.316 us; speedup vs baseline: 1.9865x; 1.0784x over previous
//
#include <hip/hip_runtime.h>
#include <hip/hip_bf16.h>
#include <math.h>

typedef __bf16 bf16;
typedef __bf16 bf16x4 __attribute__((ext_vector_type(4)));
typedef __bf16 bf16x8 __attribute__((ext_vector_type(8)));
typedef float f32x4 __attribute__((ext_vector_type(4)));

static constexpr int N_TOK = 2048;
static constexpr int B_SZ = 8;

#define MFMA(a, b, c) __builtin_amdgcn_mfma_f32_16x16x32_bf16((a), (b), (c), 0, 0, 0)

// pi: frag-friendly permutation within a 64-channel head block
// d = ks*32+hi*16+g*4+j  ->  p = ks*32+g*8+hi*4+j
__device__ __host__ __forceinline__ int pi_fwd(int d) {
  return (d & 32) | ((d & 12) << 1) | ((d & 16) >> 2) | (d & 3);
}
__device__ __forceinline__ int pi_inv(int p) {
  return (p & 32) | ((p & 4) << 2) | ((p & 24) >> 1) | (p & 3);
}

// A/B operand fragment from a k-contiguous row: elem j -> k = 16*(j>>2) + ((lane>>4)<<2) + (j&3)
__device__ __forceinline__ bf16x8 load_frag(const bf16* rowp, int lane) {
  const int g = (lane >> 4) << 2;
  bf16x4 lo = *(const bf16x4*)(rowp + g);
  bf16x4 hi = *(const bf16x4*)(rowp + g + 16);
  return __builtin_shufflevector(lo, hi, 0, 1, 2, 3, 4, 5, 6, 7);
}

// ---------------- transpose + convert: [b][256][2048] f32 -> [b][2048][256] bf16 ----------------
__global__ __launch_bounds__(256) void transpose_cvt(const float* __restrict__ in,
                                                     bf16* __restrict__ outT) {
  const int n0 = blockIdx.x * 64, c0 = blockIdx.y * 64, b = blockIdx.z;
  const int t = threadIdx.x;
  __shared__ bf16 T[64][72];
  {
    int c = t >> 2, nc = (t & 3) * 16;
    const float* src = in + ((long)b * 256 + c0 + c) * N_TOK + n0 + nc;
#pragma unroll
    for (int q = 0; q < 4; ++q) {
      float4 v = *(const float4*)(src + q * 4);
      T[c][nc + q * 4 + 0] = (bf16)v.x;
      T[c][nc + q * 4 + 1] = (bf16)v.y;
      T[c][nc + q * 4 + 2] = (bf16)v.z;
      T[c][nc + q * 4 + 3] = (bf16)v.w;
    }
  }
  __syncthreads();
  {
    int n = t >> 2, cc = (t & 3) * 16;
    bf16x8 o0, o1;
#pragma unroll
    for (int j = 0; j < 8; ++j) { o0[j] = T[cc + j][n]; o1[j] = T[cc + 8 + j][n]; }
    bf16* dst = outT + ((long)b * N_TOK + n0 + n) * 256 + c0 + cc;
    *(bf16x8*)dst = o0;
    *(bf16x8*)(dst + 8) = o1;
  }
}

// ---------------- weight prep: convert + head permutation (+pi for Q/K) ----------------
__global__ void prep_kernel(const float* __restrict__ Wq, const float* __restrict__ Wk,
                            const float* __restrict__ Wv, const float* __restrict__ Wm,
                            const float* __restrict__ W1, const float* __restrict__ W2,
                            const float* __restrict__ bq, const float* __restrict__ bk,
                            const float* __restrict__ bv,
                            bf16* __restrict__ Wqp, bf16* __restrict__ Wkp,
                            bf16* __restrict__ Wvp, bf16* __restrict__ Wmp,
                            bf16* __restrict__ W1b, bf16* __restrict__ W2b,
                            float* __restrict__ bqp, float* __restrict__ bkp,
                            float* __restrict__ bvp) {
  int i = blockIdx.x * 256 + threadIdx.x;
  if (i < 65536) {
    int cp = i >> 8, k = i & 255;
    int hh = cp >> 6, pp = cp & 63;
    int d = pi_inv(pp);
    int srcQK = (d * 4 + hh) * 256 + k;
    Wqp[i] = (bf16)Wq[srcQK];
    Wkp[i] = (bf16)Wk[srcQK];
    int srcV = (((cp & 63) << 2) | (cp >> 6)) * 256 + k;
    Wvp[i] = (bf16)Wv[srcV];
    int m = i >> 8, c2 = i & 255;
    Wmp[i] = (bf16)Wm[m * 256 + (((c2 & 63) << 2) | (c2 >> 6))];
  } else if (i < 65536 + 262144) {
    int j = i - 65536;
    W1b[j] = (bf16)W1[j];
  } else if (i < 65536 + 262144 + 131072) {
    int j = i - 327680;
    W2b[j] = (bf16)W2[j];
  } else if (i < 65536 + 262144 + 131072 + 256) {
    int c2 = i - 458752;
    int hh = c2 >> 6, pp = c2 & 63;
    int d = pi_inv(pp);
    bqp[c2] = bq[d * 4 + hh];
    bkp[c2] = bk[d * 4 + hh];
    bvp[c2] = bv[(c2 & 63) * 4 + (c2 >> 6)];
  }
}

// ---------------- generic TN GEMM: C[i][j] = sum_k A[i][k] * B[j][k] + bias ----------------
__global__ __launch_bounds__(256) void gemm_tn(
    const bf16* __restrict__ A0, const bf16* __restrict__ A1, int cSplit, long batchA,
    const bf16* __restrict__ B, long batchB,
    const float* __restrict__ bias, int biasOnCol, int permCols,
    void* __restrict__ outp, int outF32, long outR, long batchOut, int K) {
  const int j0 = blockIdx.x * 64;
  const int i0 = blockIdx.y * 64;
  const int b = blockIdx.z;
  const int t = threadIdx.x;
  const int lane = t & 63, w = t >> 6;
  const int wi = (w >> 1) * 32, wj = (w & 1) * 32;
  __shared__ bf16 As[64][40], Bs[64][40];
  f32x4 acc[2][2] = {};
  const int sr = t >> 2, sc = (t & 3) * 8;
  const bf16* A0b = A0 + (long)b * batchA;
  const bf16* A1b = A1 ? A1 + (long)b * batchA : nullptr;
  const bf16* Bb = B + (long)b * batchB;

  for (int k0 = 0; k0 < K; k0 += 32) {
    __syncthreads();
    int kk = k0 + sc;
    const bf16* asrc = (kk < cSplit) ? A0b + (long)(i0 + sr) * cSplit + kk
                                     : A1b + (long)(i0 + sr) * (K - cSplit) + (kk - cSplit);
    *(bf16x8*)&As[sr][sc] = *(const bf16x8*)asrc;
    *(bf16x8*)&Bs[sr][sc] = *(const bf16x8*)(Bb + (long)(j0 + sr) * K + kk);
    __syncthreads();
    bf16x8 a0 = load_frag(&As[wi + (lane & 15)][0], lane);
    bf16x8 a1 = load_frag(&As[wi + 16 + (lane & 15)][0], lane);
    bf16x8 b0 = load_frag(&Bs[wj + (lane & 15)][0], lane);
    bf16x8 b1 = load_frag(&Bs[wj + 16 + (lane & 15)][0], lane);
    acc[0][0] = MFMA(a0, b0, acc[0][0]);
    acc[0][1] = MFMA(a0, b1, acc[0][1]);
    acc[1][0] = MFMA(a1, b0, acc[1][0]);
    acc[1][1] = MFMA(a1, b1, acc[1][1]);
  }

  float* outf = (float*)outp;
  bf16* outb = (bf16*)outp;
  const int g4 = (lane >> 4) << 2;
#pragma unroll
  for (int fm = 0; fm < 2; ++fm)
#pragma unroll
    for (int fn = 0; fn < 2; ++fn)
#pragma unroll
      for (int r = 0; r < 4; ++r) {
        int i = i0 + wi + fm * 16 + g4 + r;
        int j = j0 + wj + fn * 16 + (lane & 15);
        float v = acc[fm][fn][r] + (bias ? bias[biasOnCol ? j : i] : 0.f);
        int js = permCols ? ((j & ~63) | pi_fwd(j & 63)) : j;
        long idx = (long)b * batchOut + (long)i * outR + js;
        if (outF32) outf[idx] = v;
        else outb[idx] = (bf16)v;
      }
}

// ---------------- flash attention v4 ----------------
// qT/kT: [b][n][h*64+p] token-major, head channels pi-permuted
// Vp: [b][c'][m] channel-major, m pi-permuted within 64-tiles
// out aT: [b][n][c'] (c' = h*64+d, old head layout)
__global__ __launch_bounds__(256, 3) void attn4_kernel(
    const bf16* __restrict__ qT, const bf16* __restrict__ kT,
    const bf16* __restrict__ Vp, bf16* __restrict__ aT) {
  const int n0 = blockIdx.x * 128;
  const int h = blockIdx.y, b = blockIdx.z;
  const int t = threadIdx.x, lane = t & 63, w = t >> 6;
  const int nl = lane & 15;
  const int g = lane >> 4, g4 = g << 2;
  __shared__ bf16 Ks[2][64][72], Vs[2][64][72];
  const float SCL = 0.125f * 1.44269504088896340736f;  // 1/sqrt(64) * log2(e)

  // Q fragments, 2 q-sets, mt-invariant (single b128 each thanks to pi)
  bf16x8 qf[2][2];
#pragma unroll
  for (int s2 = 0; s2 < 2; ++s2) {
    const bf16* qrow = qT + ((long)(b * N_TOK + n0 + s2 * 64 + 16 * w + nl)) * 256 + h * 64;
#pragma unroll
    for (int ks = 0; ks < 2; ++ks) {
      bf16x8 f = *(const bf16x8*)(qrow + ks * 32 + g * 8);
#pragma unroll
      for (int j = 0; j < 8; ++j) f[j] = (bf16)((float)f[j] * SCL);
      qf[s2][ks] = f;
    }
  }

  float m_r[2] = {-INFINITY, -INFINITY};
  float l_r[2] = {0.f, 0.f};
  f32x4 o[2][4] = {};

  const int strow = t >> 2, ste = (t & 3) * 16;
  const bf16* kbase = kT + ((long)(b * N_TOK) + strow) * 256 + h * 64 + ste;
  const bf16* vbase = Vp + ((long)(b * 256 + h * 64 + strow)) * N_TOK + ste;

  // prologue: stage tile 0
  bf16x8 rk0 = *(const bf16x8*)kbase, rk1 = *(const bf16x8*)(kbase + 8);
  bf16x8 rv0 = *(const bf16x8*)vbase, rv1 = *(const bf16x8*)(vbase + 8);
  *(bf16x8*)&Ks[0][strow][ste] = rk0;
  *(bf16x8*)&Ks[0][strow][ste + 8] = rk1;
  *(bf16x8*)&Vs[0][strow][ste] = rv0;
  *(bf16x8*)&Vs[0][strow][ste + 8] = rv1;
  __syncthreads();

  for (int mt = 0; mt < 32; ++mt) {
    const int cur = mt & 1;
    if (mt < 31) {  // issue next-tile loads early (latency hides under compute)
      const bf16* kp = kbase + (long)(mt + 1) * 64 * 256;
      const bf16* vp = vbase + (mt + 1) * 64;
      rk0 = *(const bf16x8*)kp;
      rk1 = *(const bf16x8*)(kp + 8);
      rv0 = *(const bf16x8*)vp;
      rv1 = *(const bf16x8*)(vp + 8);
    }

    // QK^T for both q-sets; K-frag read shared (single conflict-free b128)
    f32x4 sc0[4], sc1[4];
#pragma unroll
    for (int f = 0; f < 4; ++f) {
      sc0[f] = (f32x4){0.f, 0.f, 0.f, 0.f};
      sc1[f] = (f32x4){0.f, 0.f, 0.f, 0.f};
#pragma unroll
      for (int ks = 0; ks < 2; ++ks) {
        bf16x8 kf = *(const bf16x8*)&Ks[cur][16 * f + nl][ks * 32 + g * 8];
        sc0[f] = MFMA(kf, qf[0][ks], sc0[f]);
        sc1[f] = MFMA(kf, qf[1][ks], sc1[f]);
      }
    }

    bf16x8 pb[2][2];
    auto softmax = [&](f32x4* sc, int s2, bf16x8* pbs) {
      float mx = sc[0][0];
#pragma unroll
      for (int f = 0; f < 4; ++f)
#pragma unroll
        for (int r = 0; r < 4; ++r) mx = fmaxf(mx, sc[f][r]);
      mx = fmaxf(mx, __shfl_xor(mx, 16));
      mx = fmaxf(mx, __shfl_xor(mx, 32));
      if (!__all(mx <= m_r[s2] + 8.f)) {  // defer-max: skip rescale when stable
        float mn = fmaxf(m_r[s2], mx);
        float fac = exp2f(m_r[s2] - mn);
        m_r[s2] = mn;
        l_r[s2] *= fac;
#pragma unroll
        for (int f2 = 0; f2 < 4; ++f2)
#pragma unroll
          for (int r = 0; r < 4; ++r) o[s2][f2][r] *= fac;
      }
      float rs = 0.f;
#pragma unroll
      for (int f = 0; f < 4; ++f)
#pragma unroll
        for (int r = 0; r < 4; ++r) {
          float pv = exp2f(sc[f][r] - m_r[s2]);
          rs += pv;
          pbs[f >> 1][(f & 1) * 4 + r] = (bf16)pv;
        }
      rs += __shfl_xor(rs, 16);
      rs += __shfl_xor(rs, 32);
      l_r[s2] += rs;
    };
    softmax(sc0, 0, pb[0]);
    softmax(sc1, 1, pb[1]);

    // PV for both sets; V-frag read shared
#pragma unroll
    for (int f2 = 0; f2 < 4; ++f2)
#pragma unroll
      for (int ks = 0; ks < 2; ++ks) {
        bf16x8 vf = *(const bf16x8*)&Vs[cur][16 * f2 + nl][ks * 32 + g * 8];
        o[0][f2] = MFMA(vf, pb[0][ks], o[0][f2]);
        o[1][f2] = MFMA(vf, pb[1][ks], o[1][f2]);
      }

    if (mt < 31) {  // write next tile to the other buffer
      *(bf16x8*)&Ks[cur ^ 1][strow][ste] = rk0;
      *(bf16x8*)&Ks[cur ^ 1][strow][ste + 8] = rk1;
      *(bf16x8*)&Vs[cur ^ 1][strow][ste] = rv0;
      *(bf16x8*)&Vs[cur ^ 1][strow][ste + 8] = rv1;
    }
    __syncthreads();
  }

  // epilogue: O^T -> aT via per-wave LDS transpose (set0 in Ks[0], set1 in Vs[0])
  float inv0 = 1.f / l_r[0], inv1 = 1.f / l_r[1];
#pragma unroll
  for (int f2 = 0; f2 < 4; ++f2)
#pragma unroll
    for (int r = 0; r < 4; ++r) {
      Ks[0][16 * w + nl][16 * f2 + g4 + r] = (bf16)(o[0][f2][r] * inv0);
      Vs[0][16 * w + nl][16 * f2 + g4 + r] = (bf16)(o[1][f2][r] * inv1);
    }
  __syncthreads();
  {
    int rr = lane >> 2, cc = (lane & 3) * 16;
    bf16x8 a0 = *(const bf16x8*)&Ks[0][16 * w + rr][cc];
    bf16x8 a1 = *(const bf16x8*)&Ks[0][16 * w + rr][cc + 8];
    bf16* dst0 = aT + ((long)(b * N_TOK + n0 + 16 * w + rr)) * 256 + h * 64 + cc;
    *(bf16x8*)dst0 = a0;
    *(bf16x8*)(dst0 + 8) = a1;
    bf16x8 b0 = *(const bf16x8*)&Vs[0][16 * w + rr][cc];
    bf16x8 b1 = *(const bf16x8*)&Vs[0][16 * w + rr][cc + 8];
    bf16* dst1 = aT + ((long)(b * N_TOK + n0 + 64 + 16 * w + rr)) * 256 + h * 64 + cc;
    *(bf16x8*)dst1 = b0;
    *(bf16x8*)(dst1 + 8) = b1;
  }
}

// ---------------- BatchNorm stats: two-stage deterministic reduction ----------------
__global__ __launch_bounds__(256) void bn_partial(const bf16* __restrict__ hT,
                                                  float* __restrict__ ps,
                                                  float* __restrict__ pss) {
  const int g = blockIdx.x;
  const int t = threadIdx.x;
  const int cg = (t & 63) * 8;
  const int w = t >> 6;
  float s[8] = {}, ss[8] = {};
  const int rend = g * 32 + 32;
  for (int r = g * 32 + w; r < rend; r += 4) {
    bf16x8 v = *(const bf16x8*)(hT + (long)r * 512 + cg);
#pragma unroll
    for (int e = 0; e < 8; ++e) {
      float f = (float)v[e];
      s[e] += f;
      ss[e] += f * f;
    }
  }
  __shared__ float red[2][4][512];
#pragma unroll
  for (int e = 0; e < 8; ++e) {
    red[0][w][cg + e] = s[e];
    red[1][w][cg + e] = ss[e];
  }
  __syncthreads();
#pragma unroll
  for (int q = 0; q < 2; ++q) {
    int c = t * 2 + q;
    ps[(long)g * 512 + c] = red[0][0][c] + red[0][1][c] + red[0][2][c] + red[0][3][c];
    pss[(long)g * 512 + c] = red[1][0][c] + red[1][1][c] + red[1][2][c] + red[1][3][c];
  }
}

__global__ __launch_bounds__(256) void bn_finalize(const float* __restrict__ ps,
                                                   const float* __restrict__ pss,
                                                   float* __restrict__ mean,
                                                   float* __restrict__ istd) {
  const int j0 = blockIdx.x * 64;
  const int t = threadIdx.x;
  const int c = j0 + (t & 63);
  const int w = t >> 6;
  float s = 0.f, ss = 0.f;
  for (int g = w; g < 512; g += 4) {
    s += ps[(long)g * 512 + c];
    ss += pss[(long)g * 512 + c];
  }
  __shared__ float red[2][4][64];
  red[0][w][t & 63] = s;
  red[1][w][t & 63] = ss;
  __syncthreads();
  if (t < 64) {
    float su = red[0][0][t] + red[0][1][t] + red[0][2][t] + red[0][3][t];
    float sq = red[1][0][t] + red[1][1][t] + red[1][2][t] + red[1][3][t];
    const float invn = 1.f / (float)(B_SZ * N_TOK);
    float mu = su * invn;
    float var = sq * invn - mu * mu;
    mean[j0 + t] = mu;
    istd[j0 + t] = rsqrtf(var + 1e-3f);
  }
}

__global__ void bn_norm2(bf16* __restrict__ hT, const float* __restrict__ mean,
                         const float* __restrict__ istd, const float* __restrict__ gamma,
                         const float* __restrict__ beta) {
  long i = ((long)blockIdx.x * 256 + threadIdx.x) * 8;
  int c = (int)(i & 511);
  bf16x8 v = *(bf16x8*)(hT + i);
#pragma unroll
  for (int e = 0; e < 8; ++e) {
    int cc = c + e;
    float f = ((float)v[e] - mean[cc]) * istd[cc] * gamma[cc] + beta[cc];
    v[e] = (bf16)fmaxf(f, 0.f);
  }
  *(bf16x8*)(hT + i) = v;
}

extern "C" void kernel_launch(void* const* d_in, const int* in_sizes, int n_in,
                              void* d_out, int out_size, void* d_ws, size_t ws_size,
                              hipStream_t stream) {
  (void)in_sizes; (void)n_in; (void)out_size; (void)ws_size;
  const float* x = (const float*)d_in[0];
  const float* source = (const float*)d_in[1];
  const float* Wq = (const float*)d_in[2];
  const float* bq = (const float*)d_in[3];
  const float* Wk = (const float*)d_in[4];
  const float* bk = (const float*)d_in[5];
  const float* Wv = (const float*)d_in[6];
  const float* bv = (const float*)d_in[7];
  const float* Wm = (const float*)d_in[8];
  const float* bm = (const float*)d_in[9];
  const float* W1 = (const float*)d_in[10];
  const float* b1 = (const float*)d_in[11];
  const float* gamma1 = (const float*)d_in[12];
  const float* beta1 = (const float*)d_in[13];
  const float* W2 = (const float*)d_in[14];
  const float* b2 = (const float*)d_in[15];
  float* out = (float*)d_out;

  char* p = (char*)d_ws;
  size_t off = 0;
  auto alloc = [&](size_t bytes) {
    void* r = p + off;
    off += (bytes + 255) & ~(size_t)255;
    return r;
  };
  const long feat = (long)B_SZ * 256 * N_TOK;  // 4,194,304
  bf16* xT = (bf16*)alloc(feat * 2);
  bf16* sT = (bf16*)alloc(feat * 2);
  bf16* qT = (bf16*)alloc(feat * 2);
  bf16* kT = (bf16*)alloc(feat * 2);
  bf16* Vp = (bf16*)alloc(feat * 2);
  bf16* aT = (bf16*)alloc(feat * 2);
  bf16* mT = (bf16*)alloc(feat * 2);
  bf16* hT = (bf16*)alloc(feat * 4);  // [16384][512]
  bf16* Wqp = (bf16*)alloc(65536 * 2);
  bf16* Wkp = (bf16*)alloc(65536 * 2);
  bf16* Wvp = (bf16*)alloc(65536 * 2);
  bf16* Wmp = (bf16*)alloc(65536 * 2);
  bf16* W1b = (bf16*)alloc(262144 * 2);
  bf16* W2b = (bf16*)alloc(131072 * 2);
  float* bqp = (float*)alloc(256 * 4);
  float* bkp = (float*)alloc(256 * 4);
  float* bvp = (float*)alloc(256 * 4);
  float* mean = (float*)alloc(512 * 4);
  float* istd = (float*)alloc(512 * 4);
  float* ps = (float*)alloc(512 * 512 * 4);
  float* pss = (float*)alloc(512 * 512 * 4);

  dim3 blk(256);
  transpose_cvt<<<dim3(32, 4, 8), blk, 0, stream>>>(x, xT);
  transpose_cvt<<<dim3(32, 4, 8), blk, 0, stream>>>(source, sT);
  prep_kernel<<<1794, blk, 0, stream>>>(Wq, Wk, Wv, Wm, W1, W2, bq, bk, bv,
                                        Wqp, Wkp, Wvp, Wmp, W1b, W2b, bqp, bkp, bvp);

  const long bAct = (long)N_TOK * 256;
  gemm_tn<<<dim3(4, 32, 8), blk, 0, stream>>>(xT, nullptr, 256, bAct, Wqp, 0, bqp, 1, 0,
                                              qT, 0, 256, bAct, 256);
  gemm_tn<<<dim3(4, 32, 8), blk, 0, stream>>>(sT, nullptr, 256, bAct, Wkp, 0, bkp, 1, 0,
                                              kT, 0, 256, bAct, 256);
  // V: channel-major output with pi-permuted m columns
  gemm_tn<<<dim3(32, 4, 8), blk, 0, stream>>>(Wvp, nullptr, 256, 0, sT, bAct, bvp, 0, 1,
                                              Vp, 0, N_TOK, bAct, 256);

  attn4_kernel<<<dim3(16, 4, 8), blk, 0, stream>>>(qT, kT, Vp, aT);

  gemm_tn<<<dim3(4, 32, 8), blk, 0, stream>>>(aT, nullptr, 256, bAct, Wmp, 0, bm, 1, 0,
                                              mT, 0, 256, bAct, 256);
  gemm_tn<<<dim3(8, 32, 8), blk, 0, stream>>>(xT, mT, 256, bAct, W1b, 0, b1, 1, 0,
                                              hT, 0, 512, (long)N_TOK * 512, 512);

  bn_partial<<<512, blk, 0, stream>>>(hT, ps, pss);
  bn_finalize<<<8, blk, 0, stream>>>(ps, pss, mean, istd);
  bn_norm2<<<4096, blk, 0, stream>>>(hT, mean, istd, gamma1, beta1);

  gemm_tn<<<dim3(32, 4, 8), blk, 0, stream>>>(W2b, nullptr, 512, 0, hT, (long)N_TOK * 512,
                                              b2, 0, 0, out, 1, N_TOK, (long)256 * N_TOK, 512);
}

// Round 6
// 241.109 us; speedup vs baseline: 2.0294x; 1.0216x over previous
//
#include <hip/hip_runtime.h>
#include <hip/hip_bf16.h>
#include <math.h>

typedef __bf16 bf16;
typedef __bf16 bf16x4 __attribute__((ext_vector_type(4)));
typedef __bf16 bf16x8 __attribute__((ext_vector_type(8)));
typedef float f32x4 __attribute__((ext_vector_type(4)));

static constexpr int N_TOK = 2048;
static constexpr int B_SZ = 8;

#define MFMA(a, b, c) __builtin_amdgcn_mfma_f32_16x16x32_bf16((a), (b), (c), 0, 0, 0)

// pi: frag-friendly permutation within a 64-channel head block
// d = ks*32+hi*16+g*4+j  ->  p = ks*32+g*8+hi*4+j
__device__ __host__ __forceinline__ int pi_fwd(int d) {
  return (d & 32) | ((d & 12) << 1) | ((d & 16) >> 2) | (d & 3);
}
__device__ __forceinline__ int pi_inv(int p) {
  return (p & 32) | ((p & 4) << 2) | ((p & 24) >> 1) | (p & 3);
}

// A/B operand fragment from a k-contiguous row: elem j -> k = 16*(j>>2) + ((lane>>4)<<2) + (j&3)
__device__ __forceinline__ bf16x8 load_frag(const bf16* rowp, int lane) {
  const int g = (lane >> 4) << 2;
  bf16x4 lo = *(const bf16x4*)(rowp + g);
  bf16x4 hi = *(const bf16x4*)(rowp + g + 16);
  return __builtin_shufflevector(lo, hi, 0, 1, 2, 3, 4, 5, 6, 7);
}

// ---------------- transpose + convert: [b][256][2048] f32 -> [b][2048][256] bf16 ----------------
__global__ __launch_bounds__(256) void transpose_cvt(const float* __restrict__ in,
                                                     bf16* __restrict__ outT) {
  const int n0 = blockIdx.x * 64, c0 = blockIdx.y * 64, b = blockIdx.z;
  const int t = threadIdx.x;
  __shared__ bf16 T[64][72];
  {
    int c = t >> 2, nc = (t & 3) * 16;
    const float* src = in + ((long)b * 256 + c0 + c) * N_TOK + n0 + nc;
#pragma unroll
    for (int q = 0; q < 4; ++q) {
      float4 v = *(const float4*)(src + q * 4);
      T[c][nc + q * 4 + 0] = (bf16)v.x;
      T[c][nc + q * 4 + 1] = (bf16)v.y;
      T[c][nc + q * 4 + 2] = (bf16)v.z;
      T[c][nc + q * 4 + 3] = (bf16)v.w;
    }
  }
  __syncthreads();
  {
    int n = t >> 2, cc = (t & 3) * 16;
    bf16x8 o0, o1;
#pragma unroll
    for (int j = 0; j < 8; ++j) { o0[j] = T[cc + j][n]; o1[j] = T[cc + 8 + j][n]; }
    bf16* dst = outT + ((long)b * N_TOK + n0 + n) * 256 + c0 + cc;
    *(bf16x8*)dst = o0;
    *(bf16x8*)(dst + 8) = o1;
  }
}

// ---------------- weight prep: convert + head permutation (+pi for Q/K) ----------------
__global__ void prep_kernel(const float* __restrict__ Wq, const float* __restrict__ Wk,
                            const float* __restrict__ Wv, const float* __restrict__ Wm,
                            const float* __restrict__ W1, const float* __restrict__ W2,
                            const float* __restrict__ bq, const float* __restrict__ bk,
                            const float* __restrict__ bv,
                            bf16* __restrict__ Wqp, bf16* __restrict__ Wkp,
                            bf16* __restrict__ Wvp, bf16* __restrict__ Wmp,
                            bf16* __restrict__ W1b, bf16* __restrict__ W2b,
                            float* __restrict__ bqp, float* __restrict__ bkp,
                            float* __restrict__ bvp) {
  int i = blockIdx.x * 256 + threadIdx.x;
  if (i < 65536) {
    int cp = i >> 8, k = i & 255;
    int hh = cp >> 6, pp = cp & 63;
    int d = pi_inv(pp);
    int srcQK = (d * 4 + hh) * 256 + k;
    Wqp[i] = (bf16)Wq[srcQK];
    Wkp[i] = (bf16)Wk[srcQK];
    int srcV = (((cp & 63) << 2) | (cp >> 6)) * 256 + k;
    Wvp[i] = (bf16)Wv[srcV];
    int m = i >> 8, c2 = i & 255;
    Wmp[i] = (bf16)Wm[m * 256 + (((c2 & 63) << 2) | (c2 >> 6))];
  } else if (i < 65536 + 262144) {
    int j = i - 65536;
    W1b[j] = (bf16)W1[j];
  } else if (i < 65536 + 262144 + 131072) {
    int j = i - 327680;
    W2b[j] = (bf16)W2[j];
  } else if (i < 65536 + 262144 + 131072 + 256) {
    int c2 = i - 458752;
    int hh = c2 >> 6, pp = c2 & 63;
    int d = pi_inv(pp);
    bqp[c2] = bq[d * 4 + hh];
    bkp[c2] = bk[d * 4 + hh];
    bvp[c2] = bv[(c2 & 63) * 4 + (c2 >> 6)];
  }
}

// ---------------- TN GEMM v2: BK=64, double-buffered LDS, register prefetch ----------------
// C[i][j] = sum_k A[i][k]*B[j][k] + bias. Optional: concat-A (cSplit), pi-permuted out cols,
// fused per-k affine+relu on B (bnSS: {scale, shift}).
__global__ __launch_bounds__(256) void gemm_tn2(
    const bf16* __restrict__ A0, const bf16* __restrict__ A1, int cSplit, long batchA,
    const bf16* __restrict__ B, long batchB,
    const float* __restrict__ bias, int biasOnCol, int permCols,
    const float2* __restrict__ bnSS,
    void* __restrict__ outp, int outF32, long outR, long batchOut, int K) {
  const int j0 = blockIdx.x * 64;
  const int i0 = blockIdx.y * 64;
  const int b = blockIdx.z;
  const int t = threadIdx.x;
  const int lane = t & 63, w = t >> 6;
  const int wi = (w >> 1) * 32, wj = (w & 1) * 32;
  const int nl = lane & 15;
  __shared__ bf16 As[2][64][72], Bs[2][64][72];
  f32x4 acc[2][2] = {};
  const int sr = t >> 2, sc = (t & 3) * 16;
  const bf16* A0b = A0 + (long)b * batchA;
  const bf16* A1b = A1 ? A1 + (long)b * batchA : nullptr;
  const bf16* Bb = B + (long)b * batchB;

  auto loadA = [&](int kk, bf16x8& r0, bf16x8& r1) {
    const bf16* asrc = (kk < cSplit) ? A0b + (long)(i0 + sr) * cSplit + kk
                                     : A1b + (long)(i0 + sr) * (K - cSplit) + (kk - cSplit);
    r0 = *(const bf16x8*)asrc;
    r1 = *(const bf16x8*)(asrc + 8);
  };
  auto loadB = [&](int kk, bf16x8& r0, bf16x8& r1) {
    const bf16* bsrc = Bb + (long)(j0 + sr) * K + kk;
    r0 = *(const bf16x8*)bsrc;
    r1 = *(const bf16x8*)(bsrc + 8);
  };
  auto bApply = [&](bf16x8& r, int kk) {
    if (bnSS) {
#pragma unroll
      for (int e = 0; e < 8; ++e) {
        float2 ssv = bnSS[kk + e];
        r[e] = (bf16)fmaxf((float)r[e] * ssv.x + ssv.y, 0.f);
      }
    }
  };

  const int nsteps = K >> 6;
  bf16x8 a0r, a1r, b0r, b1r;
  loadA(sc, a0r, a1r);
  loadB(sc, b0r, b1r);
  bApply(b0r, sc);
  bApply(b1r, sc + 8);
  *(bf16x8*)&As[0][sr][sc] = a0r;
  *(bf16x8*)&As[0][sr][sc + 8] = a1r;
  *(bf16x8*)&Bs[0][sr][sc] = b0r;
  *(bf16x8*)&Bs[0][sr][sc + 8] = b1r;
  __syncthreads();

  for (int s = 0; s < nsteps; ++s) {
    const int cur = s & 1;
    const int kk1 = (s + 1) * 64 + sc;
    if (s + 1 < nsteps) {
      loadA(kk1, a0r, a1r);
      loadB(kk1, b0r, b1r);
    }
#pragma unroll
    for (int kp = 0; kp < 2; ++kp) {
      bf16x8 af0 = load_frag(&As[cur][wi + nl][kp * 32], lane);
      bf16x8 af1 = load_frag(&As[cur][wi + 16 + nl][kp * 32], lane);
      bf16x8 bf0 = load_frag(&Bs[cur][wj + nl][kp * 32], lane);
      bf16x8 bf1 = load_frag(&Bs[cur][wj + 16 + nl][kp * 32], lane);
      acc[0][0] = MFMA(af0, bf0, acc[0][0]);
      acc[0][1] = MFMA(af0, bf1, acc[0][1]);
      acc[1][0] = MFMA(af1, bf0, acc[1][0]);
      acc[1][1] = MFMA(af1, bf1, acc[1][1]);
    }
    if (s + 1 < nsteps) {
      bApply(b0r, kk1);
      bApply(b1r, kk1 + 8);
      *(bf16x8*)&As[cur ^ 1][sr][sc] = a0r;
      *(bf16x8*)&As[cur ^ 1][sr][sc + 8] = a1r;
      *(bf16x8*)&Bs[cur ^ 1][sr][sc] = b0r;
      *(bf16x8*)&Bs[cur ^ 1][sr][sc + 8] = b1r;
    }
    __syncthreads();
  }

  float* outf = (float*)outp;
  bf16* outb = (bf16*)outp;
  const int g4 = (lane >> 4) << 2;
#pragma unroll
  for (int fm = 0; fm < 2; ++fm)
#pragma unroll
    for (int fn = 0; fn < 2; ++fn)
#pragma unroll
      for (int r = 0; r < 4; ++r) {
        int i = i0 + wi + fm * 16 + g4 + r;
        int j = j0 + wj + fn * 16 + (lane & 15);
        float v = acc[fm][fn][r] + (bias ? bias[biasOnCol ? j : i] : 0.f);
        int js = permCols ? ((j & ~63) | pi_fwd(j & 63)) : j;
        long idx = (long)b * batchOut + (long)i * outR + js;
        if (outF32) outf[idx] = v;
        else outb[idx] = (bf16)v;
      }
}

// ---------------- flash attention v5: 64 q-rows/block, grid 1024 ----------------
// qT/kT: [b][n][h*64+p] token-major, head channels pi-permuted
// Vp: [b][c'][m] channel-major, m pi-permuted within 64-tiles
// out aT: [b][n][c'] (c' = h*64+d, old head layout)
__global__ __launch_bounds__(256) void attn5_kernel(
    const bf16* __restrict__ qT, const bf16* __restrict__ kT,
    const bf16* __restrict__ Vp, bf16* __restrict__ aT) {
  const int n0 = blockIdx.x * 64;
  const int h = blockIdx.y, b = blockIdx.z;
  const int t = threadIdx.x, lane = t & 63, w = t >> 6;
  const int nl = lane & 15;
  const int g = lane >> 4, g4 = g << 2;
  __shared__ bf16 Ks[2][64][72], Vs[2][64][72];
  const float SCL = 0.125f * 1.44269504088896340736f;  // 1/sqrt(64) * log2(e)

  // Q fragments, mt-invariant (single b128 each thanks to pi)
  bf16x8 qf[2];
  {
    const bf16* qrow = qT + ((long)(b * N_TOK + n0 + 16 * w + nl)) * 256 + h * 64;
#pragma unroll
    for (int ks = 0; ks < 2; ++ks) {
      bf16x8 f = *(const bf16x8*)(qrow + ks * 32 + g * 8);
#pragma unroll
      for (int j = 0; j < 8; ++j) f[j] = (bf16)((float)f[j] * SCL);
      qf[ks] = f;
    }
  }

  float m_r = -INFINITY, l_r = 0.f;
  f32x4 o[4] = {};

  const int strow = t >> 2, ste = (t & 3) * 16;
  const bf16* kbase = kT + ((long)(b * N_TOK) + strow) * 256 + h * 64 + ste;
  const bf16* vbase = Vp + ((long)(b * 256 + h * 64 + strow)) * N_TOK + ste;

  // prologue: stage tile 0
  bf16x8 rk0 = *(const bf16x8*)kbase, rk1 = *(const bf16x8*)(kbase + 8);
  bf16x8 rv0 = *(const bf16x8*)vbase, rv1 = *(const bf16x8*)(vbase + 8);
  *(bf16x8*)&Ks[0][strow][ste] = rk0;
  *(bf16x8*)&Ks[0][strow][ste + 8] = rk1;
  *(bf16x8*)&Vs[0][strow][ste] = rv0;
  *(bf16x8*)&Vs[0][strow][ste + 8] = rv1;
  __syncthreads();

  for (int mt = 0; mt < 32; ++mt) {
    const int cur = mt & 1;
    if (mt < 31) {  // issue next-tile loads early
      const bf16* kp = kbase + (long)(mt + 1) * 64 * 256;
      const bf16* vp = vbase + (mt + 1) * 64;
      rk0 = *(const bf16x8*)kp;
      rk1 = *(const bf16x8*)(kp + 8);
      rv0 = *(const bf16x8*)vp;
      rv1 = *(const bf16x8*)(vp + 8);
    }

    // QK^T: lane holds St[16f+g4+r][16w+nl]
    f32x4 sc[4];
#pragma unroll
    for (int f = 0; f < 4; ++f) {
      sc[f] = (f32x4){0.f, 0.f, 0.f, 0.f};
#pragma unroll
      for (int ks = 0; ks < 2; ++ks) {
        bf16x8 kf = *(const bf16x8*)&Ks[cur][16 * f + nl][ks * 32 + g * 8];
        sc[f] = MFMA(kf, qf[ks], sc[f]);
      }
    }

    // lane-local softmax
    float mx = sc[0][0];
#pragma unroll
    for (int f = 0; f < 4; ++f)
#pragma unroll
      for (int r = 0; r < 4; ++r) mx = fmaxf(mx, sc[f][r]);
    mx = fmaxf(mx, __shfl_xor(mx, 16));
    mx = fmaxf(mx, __shfl_xor(mx, 32));

    if (!__all(mx <= m_r + 8.f)) {  // defer-max
      float mn = fmaxf(m_r, mx);
      float fac = exp2f(m_r - mn);
      m_r = mn;
      l_r *= fac;
#pragma unroll
      for (int f2 = 0; f2 < 4; ++f2)
#pragma unroll
        for (int r = 0; r < 4; ++r) o[f2][r] *= fac;
    }
    bf16x8 pb[2];
    float rs = 0.f;
#pragma unroll
    for (int f = 0; f < 4; ++f)
#pragma unroll
      for (int r = 0; r < 4; ++r) {
        float pv = exp2f(sc[f][r] - m_r);
        rs += pv;
        pb[f >> 1][(f & 1) * 4 + r] = (bf16)pv;
      }
    rs += __shfl_xor(rs, 16);
    rs += __shfl_xor(rs, 32);
    l_r += rs;

    // PV: O^T[d][n] += V · P
#pragma unroll
    for (int f2 = 0; f2 < 4; ++f2)
#pragma unroll
      for (int ks = 0; ks < 2; ++ks) {
        bf16x8 vf = *(const bf16x8*)&Vs[cur][16 * f2 + nl][ks * 32 + g * 8];
        o[f2] = MFMA(vf, pb[ks], o[f2]);
      }

    if (mt < 31) {
      *(bf16x8*)&Ks[cur ^ 1][strow][ste] = rk0;
      *(bf16x8*)&Ks[cur ^ 1][strow][ste + 8] = rk1;
      *(bf16x8*)&Vs[cur ^ 1][strow][ste] = rv0;
      *(bf16x8*)&Vs[cur ^ 1][strow][ste + 8] = rv1;
    }
    __syncthreads();
  }

  // epilogue: O^T -> aT via per-wave LDS transpose
  float inv = 1.f / l_r;
#pragma unroll
  for (int f2 = 0; f2 < 4; ++f2)
#pragma unroll
    for (int r = 0; r < 4; ++r)
      Ks[0][16 * w + nl][16 * f2 + g4 + r] = (bf16)(o[f2][r] * inv);
  __syncthreads();
  {
    int rr = lane >> 2, cc = (lane & 3) * 16;
    bf16x8 a0 = *(const bf16x8*)&Ks[0][16 * w + rr][cc];
    bf16x8 a1 = *(const bf16x8*)&Ks[0][16 * w + rr][cc + 8];
    bf16* dst = aT + ((long)(b * N_TOK + n0 + 16 * w + rr)) * 256 + h * 64 + cc;
    *(bf16x8*)dst = a0;
    *(bf16x8*)(dst + 8) = a1;
  }
}

// ---------------- BatchNorm stats: two-stage deterministic reduction ----------------
__global__ __launch_bounds__(256) void bn_partial(const bf16* __restrict__ hT,
                                                  float* __restrict__ ps,
                                                  float* __restrict__ pss) {
  const int g = blockIdx.x;
  const int t = threadIdx.x;
  const int cg = (t & 63) * 8;
  const int w = t >> 6;
  float s[8] = {}, ss[8] = {};
  const int rend = g * 32 + 32;
  for (int r = g * 32 + w; r < rend; r += 4) {
    bf16x8 v = *(const bf16x8*)(hT + (long)r * 512 + cg);
#pragma unroll
    for (int e = 0; e < 8; ++e) {
      float f = (float)v[e];
      s[e] += f;
      ss[e] += f * f;
    }
  }
  __shared__ float red[2][4][512];
#pragma unroll
  for (int e = 0; e < 8; ++e) {
    red[0][w][cg + e] = s[e];
    red[1][w][cg + e] = ss[e];
  }
  __syncthreads();
#pragma unroll
  for (int q = 0; q < 2; ++q) {
    int c = t * 2 + q;
    ps[(long)g * 512 + c] = red[0][0][c] + red[0][1][c] + red[0][2][c] + red[0][3][c];
    pss[(long)g * 512 + c] = red[1][0][c] + red[1][1][c] + red[1][2][c] + red[1][3][c];
  }
}

// Stage B: reduce partials; emit fused affine {scale, shift} for BN+ReLU in MLP2
__global__ __launch_bounds__(256) void bn_finalize(const float* __restrict__ ps,
                                                   const float* __restrict__ pss,
                                                   const float* __restrict__ gamma,
                                                   const float* __restrict__ beta,
                                                   float2* __restrict__ ssbuf) {
  const int j0 = blockIdx.x * 64;
  const int t = threadIdx.x;
  const int c = j0 + (t & 63);
  const int w = t >> 6;
  float s = 0.f, ss = 0.f;
  for (int g = w; g < 512; g += 4) {
    s += ps[(long)g * 512 + c];
    ss += pss[(long)g * 512 + c];
  }
  __shared__ float red[2][4][64];
  red[0][w][t & 63] = s;
  red[1][w][t & 63] = ss;
  __syncthreads();
  if (t < 64) {
    float su = red[0][0][t] + red[0][1][t] + red[0][2][t] + red[0][3][t];
    float sq = red[1][0][t] + red[1][1][t] + red[1][2][t] + red[1][3][t];
    const float invn = 1.f / (float)(B_SZ * N_TOK);
    float mu = su * invn;
    float var = sq * invn - mu * mu;
    float istd = rsqrtf(var + 1e-3f);
    int cc = j0 + t;
    float scl = istd * gamma[cc];
    ssbuf[cc] = make_float2(scl, beta[cc] - mu * scl);
  }
}

extern "C" void kernel_launch(void* const* d_in, const int* in_sizes, int n_in,
                              void* d_out, int out_size, void* d_ws, size_t ws_size,
                              hipStream_t stream) {
  (void)in_sizes; (void)n_in; (void)out_size; (void)ws_size;
  const float* x = (const float*)d_in[0];
  const float* source = (const float*)d_in[1];
  const float* Wq = (const float*)d_in[2];
  const float* bq = (const float*)d_in[3];
  const float* Wk = (const float*)d_in[4];
  const float* bk = (const float*)d_in[5];
  const float* Wv = (const float*)d_in[6];
  const float* bv = (const float*)d_in[7];
  const float* Wm = (const float*)d_in[8];
  const float* bm = (const float*)d_in[9];
  const float* W1 = (const float*)d_in[10];
  const float* b1 = (const float*)d_in[11];
  const float* gamma1 = (const float*)d_in[12];
  const float* beta1 = (const float*)d_in[13];
  const float* W2 = (const float*)d_in[14];
  const float* b2 = (const float*)d_in[15];
  float* out = (float*)d_out;

  char* p = (char*)d_ws;
  size_t off = 0;
  auto alloc = [&](size_t bytes) {
    void* r = p + off;
    off += (bytes + 255) & ~(size_t)255;
    return r;
  };
  const long feat = (long)B_SZ * 256 * N_TOK;  // 4,194,304
  bf16* xT = (bf16*)alloc(feat * 2);
  bf16* sT = (bf16*)alloc(feat * 2);
  bf16* qT = (bf16*)alloc(feat * 2);
  bf16* kT = (bf16*)alloc(feat * 2);
  bf16* Vp = (bf16*)alloc(feat * 2);
  bf16* aT = (bf16*)alloc(feat * 2);
  bf16* mT = (bf16*)alloc(feat * 2);
  bf16* hT = (bf16*)alloc(feat * 4);  // [16384][512]
  bf16* Wqp = (bf16*)alloc(65536 * 2);
  bf16* Wkp = (bf16*)alloc(65536 * 2);
  bf16* Wvp = (bf16*)alloc(65536 * 2);
  bf16* Wmp = (bf16*)alloc(65536 * 2);
  bf16* W1b = (bf16*)alloc(262144 * 2);
  bf16* W2b = (bf16*)alloc(131072 * 2);
  float* bqp = (float*)alloc(256 * 4);
  float* bkp = (float*)alloc(256 * 4);
  float* bvp = (float*)alloc(256 * 4);
  float2* ssbuf = (float2*)alloc(512 * 8);
  float* ps = (float*)alloc(512 * 512 * 4);
  float* pss = (float*)alloc(512 * 512 * 4);

  dim3 blk(256);
  transpose_cvt<<<dim3(32, 4, 8), blk, 0, stream>>>(x, xT);
  transpose_cvt<<<dim3(32, 4, 8), blk, 0, stream>>>(source, sT);
  prep_kernel<<<1794, blk, 0, stream>>>(Wq, Wk, Wv, Wm, W1, W2, bq, bk, bv,
                                        Wqp, Wkp, Wvp, Wmp, W1b, W2b, bqp, bkp, bvp);

  const long bAct = (long)N_TOK * 256;
  // q/k projections: C[n][c'] token-major
  gemm_tn2<<<dim3(4, 32, 8), blk, 0, stream>>>(xT, nullptr, 256, bAct, Wqp, 0, bqp, 1, 0,
                                               nullptr, qT, 0, 256, bAct, 256);
  gemm_tn2<<<dim3(4, 32, 8), blk, 0, stream>>>(sT, nullptr, 256, bAct, Wkp, 0, bkp, 1, 0,
                                               nullptr, kT, 0, 256, bAct, 256);
  // v projection: C[c'][m] channel-major, pi-permuted m columns
  gemm_tn2<<<dim3(32, 4, 8), blk, 0, stream>>>(Wvp, nullptr, 256, 0, sT, bAct, bvp, 0, 1,
                                               nullptr, Vp, 0, N_TOK, bAct, 256);

  attn5_kernel<<<dim3(32, 4, 8), blk, 0, stream>>>(qT, kT, Vp, aT);

  // message projection: C[n][m] token-major
  gemm_tn2<<<dim3(4, 32, 8), blk, 0, stream>>>(aT, nullptr, 256, bAct, Wmp, 0, bm, 1, 0,
                                               nullptr, mT, 0, 256, bAct, 256);
  // MLP1 on concat([xT, mT]): C[n][512] token-major
  gemm_tn2<<<dim3(8, 32, 8), blk, 0, stream>>>(xT, mT, 256, bAct, W1b, 0, b1, 1, 0,
                                               nullptr, hT, 0, 512, (long)N_TOK * 512, 512);

  bn_partial<<<512, blk, 0, stream>>>(hT, ps, pss);
  bn_finalize<<<8, blk, 0, stream>>>(ps, pss, gamma1, beta1, ssbuf);

  // MLP2 with fused BN affine + ReLU on B-operand: C[m][n] channel-major fp32 -> d_out
  gemm_tn2<<<dim3(32, 4, 8), blk, 0, stream>>>(W2b, nullptr, 512, 0, hT, (long)N_TOK * 512,
                                               b2, 0, 0, ssbuf, out, 1, N_TOK,
                                               (long)256 * N_TOK, 512);
}